// Round 7
// baseline (168.169 us; speedup 1.0000x reference)
//
#include <hip/hip_runtime.h>
#include <stdint.h>

#define TT 2048
#define DD 768
#define NHEAD 12
#define DH 64
#define MM 8192   // B*T
#define DP 80     // padded head dim (64 data + 6 bias + 10 zero)

typedef __attribute__((ext_vector_type(8))) short bf16x8;
typedef __attribute__((ext_vector_type(4))) float f32x4;
typedef __attribute__((ext_vector_type(16))) float f32x16;
typedef __attribute__((ext_vector_type(2))) unsigned int u32x2v;
typedef unsigned short u16;

#define GAS __attribute__((address_space(1)))
#define LAS __attribute__((address_space(3)))

static __device__ __forceinline__ void gload16(const void* g, void* l) {
  __builtin_amdgcn_global_load_lds((const GAS uint32_t*)g, (LAS uint32_t*)l, 16, 0, 0);
}

static __device__ __forceinline__ u16 f2b(float f) {
  union { float f; uint32_t u; } x; x.f = f;
  uint32_t r = x.u + 0x7fffu + ((x.u >> 16) & 1u);
  return (u16)(r >> 16);
}
static __device__ __forceinline__ float b2f(u16 v) {
  union { uint32_t u; float f; } x; x.u = ((uint32_t)v) << 16; return x.f;
}

#if __has_builtin(__builtin_amdgcn_exp2f)
#define EXP2(x) __builtin_amdgcn_exp2f(x)
#else
#define EXP2(x) exp2f(x)
#endif

static __device__ __forceinline__ void pswap(uint32_t& a, uint32_t& b) {
#if __has_builtin(__builtin_amdgcn_permlane32_swap)
  u32x2v r = __builtin_amdgcn_permlane32_swap(a, b, false, false);
  a = r[0]; b = r[1];
#else
  uint32_t ax = (uint32_t)__shfl_xor((int)a, 32, 64);
  uint32_t bx = (uint32_t)__shfl_xor((int)b, 32, 64);
  bool lo = (threadIdx.x & 32) == 0;
  uint32_t na = lo ? a : bx, nb = lo ? ax : b;
  a = na; b = nb;
#endif
}
static __device__ __forceinline__ uint32_t cvtpk(float lo, float hi_) {
  uint32_t r;
  asm("v_cvt_pk_bf16_f32 %0, %1, %2" : "=v"(r) : "v"(lo), "v"(hi_));
  return r;
}
static __device__ __forceinline__ f32x16 mfma32(bf16x8 a, bf16x8 b, f32x16 c) {
  return __builtin_amdgcn_mfma_f32_32x32x16_bf16(a, b, c, 0, 0, 0);
}

// ---------------- convert f32 -> bf16 (+ fused bias-dims fill) ----------------
__global__ __launch_bounds__(256) void convert_kernel(
    const float* __restrict__ H, const float* __restrict__ wq,
    const float* __restrict__ wk, const float* __restrict__ wv,
    const float* __restrict__ wo,
    const float* __restrict__ p, const float* __restrict__ s,
    const float* __restrict__ compat, const float* __restrict__ gamma,
    u16* __restrict__ Hb, u16* __restrict__ Wqkv, u16* __restrict__ Wob,
    u16* __restrict__ Qp, u16* __restrict__ Kp) {
  const size_t NHEL = (size_t)MM * DD;
  const size_t NW = (size_t)DD * DD;
  if (blockIdx.x >= 8448) {
    // ---- bias dims: Qp/Kp dims 64..79 ----
    int i = (blockIdx.x - 8448) * 256 + threadIdx.x;
    if (i >= MM) return;
    int b = i >> 11, t = i & (TT - 1);
    const float L2E = 1.44269504f;
    float p0 = p[(size_t)i * 2], p1 = p[(size_t)i * 2 + 1], sv = s[i];
    u16 p0h = f2b(p0); u16 p0l = f2b(p0 - b2f(p0h));
    u16 p1h = f2b(p1); u16 p1l = f2b(p1 - b2f(p1h));
    u16 svh = f2b(sv); u16 svl = f2b(sv - b2f(svh));
    u16 gmb = f2b(gamma[0] * L2E);
    union { u16 u[8]; uint4 v; } kv, qv, zz;
#pragma unroll
    for (int z = 0; z < 8; ++z) zz.u[z] = 0;
    kv.u[0] = p0h; kv.u[1] = p0l; kv.u[2] = p1h; kv.u[3] = p1l;
    kv.u[4] = svh; kv.u[5] = svl; kv.u[6] = 0; kv.u[7] = 0;
#pragma unroll
    for (int h = 0; h < NHEAD; ++h) {
      float c00 = compat[h * 4 + 0], c01 = compat[h * 4 + 1];
      float c10 = compat[h * 4 + 2], c11 = compat[h * 4 + 3];
      u16 q0 = f2b((p0 * c00 + p1 * c10) * L2E);
      u16 q1 = f2b((p0 * c01 + p1 * c11) * L2E);
      qv.u[0] = q0; qv.u[1] = q0; qv.u[2] = q1; qv.u[3] = q1;
      qv.u[4] = gmb; qv.u[5] = gmb; qv.u[6] = 0; qv.u[7] = 0;
      size_t row = ((size_t)(b * NHEAD + h) * TT + t) * DP;
      *(uint4*)&Qp[row + 64] = qv.v;
      *(uint4*)&Qp[row + 72] = zz.v;
      *(uint4*)&Kp[row + 64] = kv.v;
      *(uint4*)&Kp[row + 72] = zz.v;
    }
    return;
  }
  size_t i = ((size_t)blockIdx.x * 256 + threadIdx.x) * 4;
  const float* src; u16* dst; size_t so, dofs;
  if (i < NHEL) { src = H; so = i; dst = Hb; dofs = i; }
  else if (i < NHEL + 3 * NW) {
    size_t j = i - NHEL; dst = Wqkv; dofs = j;
    if (j < NW) { src = wq; so = j; }
    else if (j < 2 * NW) { src = wk; so = j - NW; }
    else { src = wv; so = j - 2 * NW; }
  } else if (i < NHEL + 4 * NW) {
    size_t j = i - NHEL - 3 * NW; src = wo; so = j; dst = Wob; dofs = j;
  } else return;
  float4 v = *(const float4*)&src[so];
  ushort4 o;
  o.x = f2b(v.x); o.y = f2b(v.y); o.z = f2b(v.z); o.w = f2b(v.w);
  *(ushort4*)&dst[dofs] = o;
}

// ---------------- GEMM: C = A(Mx768) * Bw(Nx768)^T ----------------
// MODE 0: A=Hb, Bw=[wq;wk;wv] (N=2304). Epilogue restages the C-tile in LDS
//         and writes Q (DP-strided, *0.125*log2e), K (DP-strided), and
//         V TRANSPOSED (b,h,dh,t) with fully-coalesced 128-256B chunks.
// MODE 1: A=Ctx, Bw=Wob (N=768), Out = acc + bo (f32, direct writes)
template <int MODE>
__global__ __launch_bounds__(256) void gemm_kernel(
    const u16* __restrict__ A, const u16* __restrict__ Bw,
    u16* __restrict__ Qp, u16* __restrict__ Kp, u16* __restrict__ Vt,
    const float* __restrict__ bo, float* __restrict__ Out) {
  __shared__ u16 SMEM[17408];                 // As(8192 u16) + Bs(8192 u16); Ct overlays (128*136)
  u16* As = SMEM;
  u16* Bs = SMEM + 8192;
  const int tid = threadIdx.x;
  const int lane = tid & 63, w = tid >> 6;
  const int wr = w >> 1, wc = w & 1;
  const int g = lane >> 4, r = lane & 15;
  const int m0 = blockIdx.x * 128, n0 = blockIdx.y * 128;

  f32x4 acc[4][4];
#pragma unroll
  for (int m = 0; m < 4; ++m)
#pragma unroll
    for (int n = 0; n < 4; ++n) acc[m][n] = (f32x4){0.f, 0.f, 0.f, 0.f};

  for (int ks = 0; ks < 12; ++ks) {
    const int k0 = ks * 64;
    __syncthreads();
#pragma unroll
    for (int ii = 0; ii < 4; ++ii) {
      int seg = (w * 4 + ii) * 64 + lane;
      int row = seg >> 3, cs = seg & 7;
      int csw = cs ^ (row & 7);
      // each gload16 covers 64 lanes x 16B = 1024B = 512 u16 -> dest stride *512
      gload16(&A[(size_t)(m0 + row) * DD + k0 + csw * 8], &As[(w * 4 + ii) * 512]);
      gload16(&Bw[(size_t)(n0 + row) * DD + k0 + csw * 8], &Bs[(w * 4 + ii) * 512]);
    }
    __syncthreads();
#pragma unroll
    for (int kk = 0; kk < 2; ++kk) {
      bf16x8 af[4], bfr[4];
#pragma unroll
      for (int m = 0; m < 4; ++m) {
        int row = wr * 64 + m * 16 + r;
        int ch = (kk * 4 + g) ^ (row & 7);
        af[m] = *(const bf16x8*)&As[row * 64 + ch * 8];
      }
#pragma unroll
      for (int n = 0; n < 4; ++n) {
        int row = wc * 64 + n * 16 + r;
        int ch = (kk * 4 + g) ^ (row & 7);
        bfr[n] = *(const bf16x8*)&Bs[row * 64 + ch * 8];
      }
#pragma unroll
      for (int m = 0; m < 4; ++m)
#pragma unroll
        for (int n = 0; n < 4; ++n)
          acc[m][n] = __builtin_amdgcn_mfma_f32_16x16x32_bf16(af[m], bfr[n], acc[m][n], 0, 0, 0);
    }
  }

  if (MODE == 0) {
    // N tiles never straddle Q/K/V boundaries (768 = 6 tiles each)
    const int sel = n0 / DD;            // 0=Q 1=K 2=V
    const int e0b = n0 - sel * DD;      // head-block base, h0 = e0b>>6
    const int bb = m0 >> 11;            // batch
    const int tb = m0 & (TT - 1);       // token base (multiple of 128)
    __syncthreads();                    // all LDS reads of As/Bs done
#pragma unroll
    for (int m = 0; m < 4; ++m) {
#pragma unroll
      for (int n = 0; n < 4; ++n) {
#pragma unroll
        for (int reg = 0; reg < 4; ++reg) {
          float v = acc[m][n][reg];
          int t = wr * 64 + m * 16 + g * 4 + reg;   // local token 0..127
          int c = wc * 64 + n * 16 + r;             // local N col 0..127
          u16 bv = f2b(sel == 0 ? v * 0.18033688f : v);  // Q: *0.125*log2(e)
          if (sel < 2) SMEM[t * 136 + c] = bv;      // Ct[t][c]
          else         SMEM[c * 136 + t] = bv;      // Ct[dh][t] (transposed)
        }
      }
    }
    __syncthreads();
    if (sel < 2) {
      u16* base = (sel == 0) ? Qp : Kp;
      const int grp = tid >> 3, li = tid & 7;       // 32 groups x 8 lanes
#pragma unroll
      for (int it = 0; it < 8; ++it) {
        int chunk = it * 32 + grp;                  // 0..255
        int t = chunk & 127, hh = chunk >> 7;
        int h = (e0b >> 6) + hh;
        size_t row = ((size_t)(bb * NHEAD + h) * TT + tb + t) * DP;
        uint4 d = *(const uint4*)&SMEM[t * 136 + hh * 64 + li * 8];
        *(uint4*)&base[row + li * 8] = d;
      }
    } else {
      const int grp = tid >> 4, li = tid & 15;      // 16 groups x 16 lanes
#pragma unroll
      for (int it = 0; it < 8; ++it) {
        int c = it * 16 + grp;                      // 0..127
        int h = (e0b >> 6) + (c >> 6), dh = c & 63;
        size_t row = ((size_t)(bb * NHEAD + h)) * DH * TT + (size_t)dh * TT + tb;
        uint4 d = *(const uint4*)&SMEM[c * 136 + li * 8];
        *(uint4*)&Vt[row + li * 8] = d;
      }
    }
  } else {
#pragma unroll
    for (int m = 0; m < 4; ++m) {
#pragma unroll
      for (int n = 0; n < 4; ++n) {
#pragma unroll
        for (int reg = 0; reg < 4; ++reg) {
          int gt = m0 + wr * 64 + m * 16 + g * 4 + reg;
          int e = n0 + wc * 64 + n * 16 + r;
          Out[(size_t)gt * DD + e] = acc[m][n][reg] + bo[e];
        }
      }
    }
  }
}

// ---------------- attention: (qg,kh)-split waves, high occupancy ----------------
// 4 waves: wave (qg, kh) handles 32 q x 32 keys of each 64-key tile.
// Swapped QK^T, fixed-base softmax (m=0). Halved per-wave register state
// (~115 VGPR+AGPR total) targets 4 waves/SIMD under launch_bounds(256,4).
// kh-halves combine O through an LDS overlay once at the end.
#define QBLK 64
__global__ __launch_bounds__(256, 4) void attn_kernel(
    const u16* __restrict__ Qp, const u16* __restrict__ Kp, const u16* __restrict__ Vtb,
    u16* __restrict__ Ctx) {
  __shared__ char SMC[38912];
  u16* KsBase = (u16*)SMC;              // 2 x 64 x 88 u16 = 22528 B
  u16* VsBase = (u16*)(SMC + 22528);    // 2 x 64 x 64 u16 = 16384 B
  float* OsF = (float*)SMC;             // epilogue overlay: 64*64 f32 = 16384 B
  float* LsF = (float*)(SMC + 16384);   // 64*4 f32 = 1024 B

  const int tid = threadIdx.x, lane = tid & 63, w = tid >> 6;
  const int qg = w & 1, kh = w >> 1;    // q-group (32 q), key-half (32 keys)
  const int hi = lane >> 5, ql = lane & 31;
  const int bid = blockIdx.x;
  const int bh = bid % 48, qb = bid / 48;   // bh-major: same bh -> same XCD
  const int b = bh / NHEAD, h = bh % NHEAD;

  const char* KgB = (const char*)(Kp + (size_t)bh * TT * DP);
  const char* VgB = (const char*)(Vtb + (size_t)bh * DH * TT);
  const u16* Qg = Qp + (size_t)bh * TT * DP;

  // Q' fragments for this wave's 32 q
  const int q0r = qb * QBLK + qg * 32 + ql;
  bf16x8 Qf[5];
#pragma unroll
  for (int kbl = 0; kbl < 5; ++kbl)
    Qf[kbl] = *(const bf16x8*)&Qg[(size_t)q0r * DP + (2 * kbl + hi) * 8];

  auto STAGE = [&](int nb, int t0) {
    const char* ksrc = KgB + (size_t)t0 * 160;
    char* kd = (char*)(KsBase + nb * (64 * 88));
#pragma unroll
    for (int i = 0; i < 3; ++i) {                  // K: 11 chunks over 4 waves
      int idx = w + 4 * i;
      if (idx < 11) {
        int n = idx * 64 + lane;
        int rr = (n * 2979) >> 15;                 // n/11 exact for n<768
        int c = n - 11 * rr; if (c > 9) c = 9;
        gload16(ksrc + rr * 160 + c * 16, kd + idx * 1024);
      }
    }
    const char* vsrc = VgB + (size_t)t0 * 2;
    char* vd = (char*)(VsBase + nb * (64 * 64));
#pragma unroll
    for (int j = 0; j < 2; ++j) {                  // V: 8 chunks over 4 waves
      int idx = w + 4 * j;
      int n = idx * 64 + lane;
      int dh = n >> 3, cs = n & 7;
      gload16(vsrc + dh * 4096 + ((cs ^ (dh & 7))) * 16, vd + idx * 1024);
    }
  };

  f32x16 o0, o1;                  // o[dh-half]: 32 q x 64 dh
#pragma unroll
  for (int z = 0; z < 16; ++z) { o0[z] = 0.f; o1[z] = 0.f; }
  float l0 = 0.f;                 // per-lane l partial (q=ql, own hi keys, own kh)

  STAGE(0, 0);

  for (int kt = 0; kt < 32; ++kt) {
    __syncthreads();                       // drains vmcnt: current buffers valid
    if (kt + 1 < 32) STAGE((kt + 1) & 1, (kt + 1) * 64);
    const u16* Kb_ = KsBase + (kt & 1) * (64 * 88);
    const u16* Vb_ = VsBase + (kt & 1) * (64 * 64);

    // S^T = K' Q'^T : this wave's 32 keys (rows) x 32 q (cols)
    f32x16 s0;
#pragma unroll
    for (int z = 0; z < 16; ++z) s0[z] = 0.f;
    __builtin_amdgcn_s_setprio(1);
#pragma unroll
    for (int kbl = 0; kbl < 5; ++kbl) {
      bf16x8 kf = *(const bf16x8*)&Kb_[(kh * 32 + ql) * 88 + hi * 8 + kbl * 16];
      s0 = mfma32(kf, Qf[kbl], s0);
    }
    __builtin_amdgcn_s_setprio(0);

    // P = exp2(S) (fixed base m=0); accumulate l from f32 p values
    float p_[16];
#pragma unroll
    for (int z = 0; z < 16; ++z) p_[z] = EXP2(s0[z]);
    float ts = 0.f;
#pragma unroll
    for (int z = 0; z < 16; ++z) ts += p_[z];
    l0 += ts;

    // pack PA fragments (cvt_pk + permlane32_swap): 2 local key-slots
    bf16x8 pa[2];
#pragma unroll
    for (int ks = 0; ks < 2; ++ks) {
      const int base = ks * 8;
      uint32_t wa = cvtpk(p_[base + 0], p_[base + 1]);
      uint32_t wb = cvtpk(p_[base + 4], p_[base + 5]);
      uint32_t wc = cvtpk(p_[base + 2], p_[base + 3]);
      uint32_t wd = cvtpk(p_[base + 6], p_[base + 7]);
      pswap(wa, wb); pswap(wc, wd);
      union { uint32_t u[4]; bf16x8 v; } pav;
      pav.u[0] = wa; pav.u[1] = wc; pav.u[2] = wb; pav.u[3] = wd;
      pa[ks] = pav.v;
    }

    // PV over this wave's 2 global key-slots
    __builtin_amdgcn_s_setprio(1);
#pragma unroll
    for (int ks = 0; ks < 2; ++ks) {
      const int sw = ((2 * (kh * 2 + ks) + hi) ^ (ql & 7)) * 8;
      bf16x8 vf0 = *(const bf16x8*)&Vb_[ql * 64 + sw];
      bf16x8 vf1 = *(const bf16x8*)&Vb_[(ql + 32) * 64 + sw];
      o0 = mfma32(pa[ks], vf0, o0);
      o1 = mfma32(pa[ks], vf1, o1);
    }
    __builtin_amdgcn_s_setprio(0);
  }

  // ---- kh-half combine through LDS overlay ----
  __syncthreads();   // all waves done with Ks/Vs
  if (kh == 1) {
#pragma unroll
    for (int z = 0; z < 16; ++z) {
      int q2 = (z & 3) + 8 * (z >> 2) + 4 * hi;
      OsF[(qg * 32 + q2) * 64 + ql]      = o0[z];
      OsF[(qg * 32 + q2) * 64 + ql + 32] = o1[z];
    }
  }
  LsF[(qg * 32 + ql) * 4 + kh * 2 + hi] = l0;
  __syncthreads();
  if (kh == 0) {
#pragma unroll
    for (int z = 0; z < 16; ++z) {
      int q2 = (z & 3) + 8 * (z >> 2) + 4 * hi;
      int lq = qg * 32 + q2;
      float lt = LsF[lq * 4 + 0] + LsF[lq * 4 + 1] + LsF[lq * 4 + 2] + LsF[lq * 4 + 3];
      float il = 1.0f / lt;
      float a0 = o0[z] + OsF[lq * 64 + ql];
      float a1 = o1[z] + OsF[lq * 64 + ql + 32];
      int qrow = qb * QBLK + lq;
      size_t rowb = ((size_t)b * TT + qrow) * DD + h * DH;
      Ctx[rowb + ql]      = f2b(a0 * il);
      Ctx[rowb + ql + 32] = f2b(a1 * il);
    }
  }
}

extern "C" void kernel_launch(void* const* d_in, const int* in_sizes, int n_in,
                              void* d_out, int out_size, void* d_ws, size_t ws_size,
                              hipStream_t stream) {
  const float* H = (const float*)d_in[0];
  const float* p = (const float*)d_in[1];
  const float* s = (const float*)d_in[2];
  const float* wq = (const float*)d_in[3];
  const float* wk = (const float*)d_in[4];
  const float* wv = (const float*)d_in[5];
  const float* wo = (const float*)d_in[6];
  const float* bo = (const float*)d_in[7];
  const float* compat = (const float*)d_in[8];
  const float* gamma = (const float*)d_in[9];
  float* out = (float*)d_out;

  char* ws = (char*)d_ws;
  u16* Hb   = (u16*)(ws);               // 12,582,912 B (dead after gemm<0> -> Ctx)
  u16* Wqkv = (u16*)(ws + 12582912);    //  3,538,944 B
  u16* Wob  = (u16*)(ws + 16121856);    //  1,179,648 B
  u16* Qpb  = (u16*)(ws + 17301504);    // 15,728,640 B  (B*H*T*80 bf16)
  u16* Kpb  = (u16*)(ws + 33030144);    // 15,728,640 B
  u16* Vtb  = (u16*)(ws + 48758784);    // 12,582,912 B  (written transposed by gemm<0>)
  u16* Ctx  = Hb;                       // alias: Hb dead after gemm<0>
  // total 61,341,696 B

  convert_kernel<<<8480, 256, 0, stream>>>(H, wq, wk, wv, wo, p, s, compat, gamma,
                                           Hb, Wqkv, Wob, Qpb, Kpb);
  gemm_kernel<0><<<dim3(64, 18), 256, 0, stream>>>(Hb, Wqkv, Qpb, Kpb, Vtb, nullptr, nullptr);
  attn_kernel<<<1536, 256, 0, stream>>>(Qpb, Kpb, Vtb, Ctx);
  gemm_kernel<1><<<dim3(64, 6), 256, 0, stream>>>(Ctx, Wob, nullptr, nullptr, nullptr, bo, out);
}

// Round 9
// 159.402 us; speedup vs baseline: 1.0550x; 1.0550x over previous
//
#include <hip/hip_runtime.h>
#include <stdint.h>

#define TT 2048
#define DD 768
#define NHEAD 12
#define DH 64
#define MM 8192   // B*T
#define DP 80     // padded head dim (64 data + 6 bias + 10 zero)

typedef __attribute__((ext_vector_type(8))) short bf16x8;
typedef __attribute__((ext_vector_type(4))) float f32x4;
typedef __attribute__((ext_vector_type(16))) float f32x16;
typedef __attribute__((ext_vector_type(2))) unsigned int u32x2v;
typedef unsigned short u16;

#define GAS __attribute__((address_space(1)))
#define LAS __attribute__((address_space(3)))

static __device__ __forceinline__ void gload16(const void* g, void* l) {
  __builtin_amdgcn_global_load_lds((const GAS uint32_t*)g, (LAS uint32_t*)l, 16, 0, 0);
}

static __device__ __forceinline__ u16 f2b(float f) {
  union { float f; uint32_t u; } x; x.f = f;
  uint32_t r = x.u + 0x7fffu + ((x.u >> 16) & 1u);
  return (u16)(r >> 16);
}
static __device__ __forceinline__ float b2f(u16 v) {
  union { uint32_t u; float f; } x; x.u = ((uint32_t)v) << 16; return x.f;
}

#if __has_builtin(__builtin_amdgcn_exp2f)
#define EXP2(x) __builtin_amdgcn_exp2f(x)
#else
#define EXP2(x) exp2f(x)
#endif

static __device__ __forceinline__ void pswap(uint32_t& a, uint32_t& b) {
#if __has_builtin(__builtin_amdgcn_permlane32_swap)
  u32x2v r = __builtin_amdgcn_permlane32_swap(a, b, false, false);
  a = r[0]; b = r[1];
#else
  uint32_t ax = (uint32_t)__shfl_xor((int)a, 32, 64);
  uint32_t bx = (uint32_t)__shfl_xor((int)b, 32, 64);
  bool lo = (threadIdx.x & 32) == 0;
  uint32_t na = lo ? a : bx, nb = lo ? ax : b;
  a = na; b = nb;
#endif
}
static __device__ __forceinline__ uint32_t cvtpk(float lo, float hi_) {
  uint32_t r;
  asm("v_cvt_pk_bf16_f32 %0, %1, %2" : "=v"(r) : "v"(lo), "v"(hi_));
  return r;
}
static __device__ __forceinline__ f32x16 mfma32(bf16x8 a, bf16x8 b, f32x16 c) {
  return __builtin_amdgcn_mfma_f32_32x32x16_bf16(a, b, c, 0, 0, 0);
}

// ---------------- convert f32 -> bf16 (+ fused bias-dims fill) ----------------
__global__ __launch_bounds__(256) void convert_kernel(
    const float* __restrict__ H, const float* __restrict__ wq,
    const float* __restrict__ wk, const float* __restrict__ wv,
    const float* __restrict__ wo,
    const float* __restrict__ p, const float* __restrict__ s,
    const float* __restrict__ compat, const float* __restrict__ gamma,
    u16* __restrict__ Hb, u16* __restrict__ Wqkv, u16* __restrict__ Wob,
    u16* __restrict__ Qp, u16* __restrict__ Kp) {
  const size_t NHEL = (size_t)MM * DD;
  const size_t NW = (size_t)DD * DD;
  if (blockIdx.x >= 8448) {
    // ---- bias dims: Qp/Kp dims 64..79 ----
    int i = (blockIdx.x - 8448) * 256 + threadIdx.x;
    if (i >= MM) return;
    int b = i >> 11, t = i & (TT - 1);
    const float L2E = 1.44269504f;
    float p0 = p[(size_t)i * 2], p1 = p[(size_t)i * 2 + 1], sv = s[i];
    u16 p0h = f2b(p0); u16 p0l = f2b(p0 - b2f(p0h));
    u16 p1h = f2b(p1); u16 p1l = f2b(p1 - b2f(p1h));
    u16 svh = f2b(sv); u16 svl = f2b(sv - b2f(svh));
    u16 gmb = f2b(gamma[0] * L2E);
    union { u16 u[8]; uint4 v; } kv, qv, zz;
#pragma unroll
    for (int z = 0; z < 8; ++z) zz.u[z] = 0;
    kv.u[0] = p0h; kv.u[1] = p0l; kv.u[2] = p1h; kv.u[3] = p1l;
    kv.u[4] = svh; kv.u[5] = svl; kv.u[6] = 0; kv.u[7] = 0;
#pragma unroll
    for (int h = 0; h < NHEAD; ++h) {
      float c00 = compat[h * 4 + 0], c01 = compat[h * 4 + 1];
      float c10 = compat[h * 4 + 2], c11 = compat[h * 4 + 3];
      u16 q0 = f2b((p0 * c00 + p1 * c10) * L2E);
      u16 q1 = f2b((p0 * c01 + p1 * c11) * L2E);
      qv.u[0] = q0; qv.u[1] = q0; qv.u[2] = q1; qv.u[3] = q1;
      qv.u[4] = gmb; qv.u[5] = gmb; qv.u[6] = 0; qv.u[7] = 0;
      size_t row = ((size_t)(b * NHEAD + h) * TT + t) * DP;
      *(uint4*)&Qp[row + 64] = qv.v;
      *(uint4*)&Qp[row + 72] = zz.v;
      *(uint4*)&Kp[row + 64] = kv.v;
      *(uint4*)&Kp[row + 72] = zz.v;
    }
    return;
  }
  size_t i = ((size_t)blockIdx.x * 256 + threadIdx.x) * 4;
  const float* src; u16* dst; size_t so, dofs;
  if (i < NHEL) { src = H; so = i; dst = Hb; dofs = i; }
  else if (i < NHEL + 3 * NW) {
    size_t j = i - NHEL; dst = Wqkv; dofs = j;
    if (j < NW) { src = wq; so = j; }
    else if (j < 2 * NW) { src = wk; so = j - NW; }
    else { src = wv; so = j - 2 * NW; }
  } else if (i < NHEL + 4 * NW) {
    size_t j = i - NHEL - 3 * NW; src = wo; so = j; dst = Wob; dofs = j;
  } else return;
  float4 v = *(const float4*)&src[so];
  ushort4 o;
  o.x = f2b(v.x); o.y = f2b(v.y); o.z = f2b(v.z); o.w = f2b(v.w);
  *(ushort4*)&dst[dofs] = o;
}

// ---------------- GEMM: C = A(Mx768) * Bw(Nx768)^T ----------------
// MODE 0: A=Hb, Bw=[wq;wk;wv] (N=2304). Epilogue restages the C-tile in LDS
//         and writes Q (DP-strided, *0.125*log2e), K (DP-strided), and
//         V TRANSPOSED (b,h,dh,t) with fully-coalesced 128-256B chunks.
// MODE 1: A=Ctx, Bw=Wob (N=768), Out = acc + bo (f32, direct writes)
template <int MODE>
__global__ __launch_bounds__(256) void gemm_kernel(
    const u16* __restrict__ A, const u16* __restrict__ Bw,
    u16* __restrict__ Qp, u16* __restrict__ Kp, u16* __restrict__ Vt,
    const float* __restrict__ bo, float* __restrict__ Out) {
  __shared__ u16 SMEM[17408];                 // As(8192 u16) + Bs(8192 u16); Ct overlays (128*136)
  u16* As = SMEM;
  u16* Bs = SMEM + 8192;
  const int tid = threadIdx.x;
  const int lane = tid & 63, w = tid >> 6;
  const int wr = w >> 1, wc = w & 1;
  const int g = lane >> 4, r = lane & 15;
  const int m0 = blockIdx.x * 128, n0 = blockIdx.y * 128;

  f32x4 acc[4][4];
#pragma unroll
  for (int m = 0; m < 4; ++m)
#pragma unroll
    for (int n = 0; n < 4; ++n) acc[m][n] = (f32x4){0.f, 0.f, 0.f, 0.f};

  for (int ks = 0; ks < 12; ++ks) {
    const int k0 = ks * 64;
    __syncthreads();
#pragma unroll
    for (int ii = 0; ii < 4; ++ii) {
      int seg = (w * 4 + ii) * 64 + lane;
      int row = seg >> 3, cs = seg & 7;
      int csw = cs ^ (row & 7);
      // each gload16 covers 64 lanes x 16B = 1024B = 512 u16 -> dest stride *512
      gload16(&A[(size_t)(m0 + row) * DD + k0 + csw * 8], &As[(w * 4 + ii) * 512]);
      gload16(&Bw[(size_t)(n0 + row) * DD + k0 + csw * 8], &Bs[(w * 4 + ii) * 512]);
    }
    __syncthreads();
#pragma unroll
    for (int kk = 0; kk < 2; ++kk) {
      bf16x8 af[4], bfr[4];
#pragma unroll
      for (int m = 0; m < 4; ++m) {
        int row = wr * 64 + m * 16 + r;
        int ch = (kk * 4 + g) ^ (row & 7);
        af[m] = *(const bf16x8*)&As[row * 64 + ch * 8];
      }
#pragma unroll
      for (int n = 0; n < 4; ++n) {
        int row = wc * 64 + n * 16 + r;
        int ch = (kk * 4 + g) ^ (row & 7);
        bfr[n] = *(const bf16x8*)&Bs[row * 64 + ch * 8];
      }
#pragma unroll
      for (int m = 0; m < 4; ++m)
#pragma unroll
        for (int n = 0; n < 4; ++n)
          acc[m][n] = __builtin_amdgcn_mfma_f32_16x16x32_bf16(af[m], bfr[n], acc[m][n], 0, 0, 0);
    }
  }

  if (MODE == 0) {
    const int sel = n0 / DD;            // 0=Q 1=K 2=V
    const int e0b = n0 - sel * DD;
    const int bb = m0 >> 11;
    const int tb = m0 & (TT - 1);
    __syncthreads();
#pragma unroll
    for (int m = 0; m < 4; ++m) {
#pragma unroll
      for (int n = 0; n < 4; ++n) {
#pragma unroll
        for (int reg = 0; reg < 4; ++reg) {
          float v = acc[m][n][reg];
          int t = wr * 64 + m * 16 + g * 4 + reg;
          int c = wc * 64 + n * 16 + r;
          u16 bv = f2b(sel == 0 ? v * 0.18033688f : v);  // Q: *0.125*log2(e)
          if (sel < 2) SMEM[t * 136 + c] = bv;
          else         SMEM[c * 136 + t] = bv;
        }
      }
    }
    __syncthreads();
    if (sel < 2) {
      u16* base = (sel == 0) ? Qp : Kp;
      const int grp = tid >> 3, li = tid & 7;
#pragma unroll
      for (int it = 0; it < 8; ++it) {
        int chunk = it * 32 + grp;
        int t = chunk & 127, hh = chunk >> 7;
        int h = (e0b >> 6) + hh;
        size_t row = ((size_t)(bb * NHEAD + h) * TT + tb + t) * DP;
        uint4 d = *(const uint4*)&SMEM[t * 136 + hh * 64 + li * 8];
        *(uint4*)&base[row + li * 8] = d;
      }
    } else {
      const int grp = tid >> 4, li = tid & 15;
#pragma unroll
      for (int it = 0; it < 8; ++it) {
        int c = it * 16 + grp;
        int h = (e0b >> 6) + (c >> 6), dh = c & 63;
        size_t row = ((size_t)(bb * NHEAD + h)) * DH * TT + (size_t)dh * TT + tb;
        uint4 d = *(const uint4*)&SMEM[c * 136 + li * 8];
        *(uint4*)&Vt[row + li * 8] = d;
      }
    }
  } else {
#pragma unroll
    for (int m = 0; m < 4; ++m) {
#pragma unroll
      for (int n = 0; n < 4; ++n) {
#pragma unroll
        for (int reg = 0; reg < 4; ++reg) {
          int gt = m0 + wr * 64 + m * 16 + g * 4 + reg;
          int e = n0 + wc * 64 + n * 16 + r;
          Out[(size_t)gt * DD + e] = acc[m][n][reg] + bo[e];
        }
      }
    }
  }
}

// ---------------- attention: swapped QK^T, fixed-base softmax (m=0), l via MFMA ----------------
// R4-proven structure: 4 waves x 32 q, full 64-key tile per wave, single
// barrier per tile, K/V double-buffered via global_load_lds. Scores bounded
// (|S| <~ 5 log2-units) so exp2(S) is safely in range; max-subtraction is
// rounding-neutral (2^-m exact) and dropped. l accumulates as an extra PV
// output via B=ones (row layout matches o -> no cross-lane broadcast).
#define QB 128
__global__ __launch_bounds__(256, 3) void attn_kernel(
    const u16* __restrict__ Qp, const u16* __restrict__ Kp, const u16* __restrict__ Vtb,
    u16* __restrict__ Ctx) {
  __shared__ u16 Ks[2][64 * 88];   // 64 rows x 176B (160B data + 16B pad-dup)
  __shared__ u16 Vs[2][64 * 64];   // [dh][key], source pre-swizzled
  const int tid = threadIdx.x, lane = tid & 63, w = tid >> 6;
  const int hi = lane >> 5, ql = lane & 31;
  const int bid = blockIdx.x;
  const int bh = bid % 48, qb = bid / 48;   // bh-major: same bh -> same XCD
  const int b = bh / NHEAD, h = bh % NHEAD;

  const char* KgB = (const char*)(Kp + (size_t)bh * TT * DP);
  const char* VgB = (const char*)(Vtb + (size_t)bh * DH * TT);
  const u16* Qg = Qp + (size_t)bh * TT * DP;

  const int q = qb * QB + w * 32 + ql;
  bf16x8 Qf[5];
#pragma unroll
  for (int kbl = 0; kbl < 5; ++kbl)
    Qf[kbl] = *(const bf16x8*)&Qg[(size_t)q * DP + (2 * kbl + hi) * 8];

  union { u16 u[8]; bf16x8 v; } ones;
#pragma unroll
  for (int z = 0; z < 8; ++z) ones.u[z] = 0x3F80;  // bf16 1.0

  auto kofs = [&](int i) {
    int n = i * 64 + lane;
    int rr = (n * 2979) >> 15;       // n/11 exact for n<768
    int c = n - 11 * rr; if (c > 9) c = 9;
    return rr * 160 + c * 16;
  };
  auto vofs = [&](int j) {
    int n = j * 64 + lane;
    int dh = n >> 3, cs = n & 7;
    return dh * 4096 + (cs ^ (dh & 7)) * 16;
  };
  const int koff0 = kofs(w), koff1 = kofs(w + 4), koff2 = (w < 3) ? kofs(w + 8) : 0;
  const int voff0 = vofs(w), voff1 = vofs(w + 4);

  auto STAGE = [&](int nb, int t0) {
    const char* ksrc = KgB + (size_t)t0 * 160;
    char* kd = (char*)&Ks[nb][0];
    gload16(ksrc + koff0, kd + w * 1024);
    gload16(ksrc + koff1, kd + (w + 4) * 1024);
    if (w < 3) gload16(ksrc + koff2, kd + (w + 8) * 1024);
    const char* vsrc = VgB + (size_t)t0 * 2;
    char* vd = (char*)&Vs[nb][0];
    gload16(vsrc + voff0, vd + w * 1024);
    gload16(vsrc + voff1, vd + (w + 4) * 1024);
  };

  f32x16 o0, o1, ol;
#pragma unroll
  for (int z = 0; z < 16; ++z) { o0[z] = 0.f; o1[z] = 0.f; ol[z] = 0.f; }

  STAGE(0, 0);

  for (int kt = 0; kt < 32; ++kt) {
    __syncthreads();                       // drains vmcnt: current buffers valid
    if (kt + 1 < 32) STAGE((kt + 1) & 1, (kt + 1) * 64);
    const u16* Kb_ = &Ks[kt & 1][0];
    const u16* Vb_ = &Vs[kt & 1][0];

    // S^T = K' * Q'^T : rows=keys, cols=q (lane&31). Two 32-key blocks.
    f32x16 s0, s1;
#pragma unroll
    for (int z = 0; z < 16; ++z) { s0[z] = 0.f; s1[z] = 0.f; }
    __builtin_amdgcn_s_setprio(1);
#pragma unroll
    for (int kbl = 0; kbl < 5; ++kbl) {
      bf16x8 a0 = *(const bf16x8*)&Kb_[ql * 88 + hi * 8 + kbl * 16];
      s0 = mfma32(a0, Qf[kbl], s0);
    }
#pragma unroll
    for (int kbl = 0; kbl < 5; ++kbl) {
      bf16x8 a1 = *(const bf16x8*)&Kb_[(ql + 32) * 88 + hi * 8 + kbl * 16];
      s1 = mfma32(a1, Qf[kbl], s1);
    }
    __builtin_amdgcn_s_setprio(0);

    // P = exp2(S) directly (fixed base m=0)
    float p_[32];
#pragma unroll
    for (int z = 0; z < 16; ++z) p_[z] = EXP2(s0[z]);
#pragma unroll
    for (int z = 0; z < 16; ++z) p_[16 + z] = EXP2(s1[z]);

    // build PA fragments in-register (cvt_pk + permlane32_swap); PV + l-column
    __builtin_amdgcn_s_setprio(1);
#pragma unroll
    for (int ks = 0; ks < 4; ++ks) {
      const int base = ks * 8;
      uint32_t wa = cvtpk(p_[base + 0], p_[base + 1]);
      uint32_t wb = cvtpk(p_[base + 4], p_[base + 5]);
      uint32_t wc = cvtpk(p_[base + 2], p_[base + 3]);
      uint32_t wd = cvtpk(p_[base + 6], p_[base + 7]);
      pswap(wa, wb);
      pswap(wc, wd);
      union { uint32_t u[4]; bf16x8 v; } pa;
      pa.u[0] = wa; pa.u[1] = wc; pa.u[2] = wb; pa.u[3] = wd;
#pragma unroll
      for (int nb = 0; nb < 2; ++nb) {
        int row = ql + 32 * nb;
        bf16x8 vf = *(const bf16x8*)&Vb_[row * 64 + (((2 * ks + hi) ^ (ql & 7)) * 8)];
        if (nb == 0) o0 = mfma32(pa.v, vf, o0);
        else         o1 = mfma32(pa.v, vf, o1);
      }
      ol = mfma32(pa.v, ones.v, ol);       // row-sum of P (all cols identical)
    }
    __builtin_amdgcn_s_setprio(0);
  }

  // epilogue: l is in-register in the same row layout as o0/o1 — no broadcast
#pragma unroll
  for (int z = 0; z < 16; ++z) {
    int q2 = (z & 3) + 8 * (z >> 2) + 4 * hi;
    float il = 1.0f / ol[z];
    int qrow = qb * QB + w * 32 + q2;
    size_t rowb = ((size_t)b * TT + qrow) * DD + h * DH;
    Ctx[rowb + ql]      = f2b(o0[z] * il);
    Ctx[rowb + ql + 32] = f2b(o1[z] * il);
  }
}

extern "C" void kernel_launch(void* const* d_in, const int* in_sizes, int n_in,
                              void* d_out, int out_size, void* d_ws, size_t ws_size,
                              hipStream_t stream) {
  const float* H = (const float*)d_in[0];
  const float* p = (const float*)d_in[1];
  const float* s = (const float*)d_in[2];
  const float* wq = (const float*)d_in[3];
  const float* wk = (const float*)d_in[4];
  const float* wv = (const float*)d_in[5];
  const float* wo = (const float*)d_in[6];
  const float* bo = (const float*)d_in[7];
  const float* compat = (const float*)d_in[8];
  const float* gamma = (const float*)d_in[9];
  float* out = (float*)d_out;

  char* ws = (char*)d_ws;
  u16* Hb   = (u16*)(ws);               // 12,582,912 B (dead after gemm<0> -> Ctx)
  u16* Wqkv = (u16*)(ws + 12582912);    //  3,538,944 B
  u16* Wob  = (u16*)(ws + 16121856);    //  1,179,648 B
  u16* Qpb  = (u16*)(ws + 17301504);    // 15,728,640 B  (B*H*T*80 bf16)
  u16* Kpb  = (u16*)(ws + 33030144);    // 15,728,640 B
  u16* Vtb  = (u16*)(ws + 48758784);    // 12,582,912 B  (written transposed by gemm<0>)
  u16* Ctx  = Hb;                       // alias: Hb dead after gemm<0>
  // total 61,341,696 B

  convert_kernel<<<8480, 256, 0, stream>>>(H, wq, wk, wv, wo, p, s, compat, gamma,
                                           Hb, Wqkv, Wob, Qpb, Kpb);
  gemm_kernel<0><<<dim3(64, 18), 256, 0, stream>>>(Hb, Wqkv, Qpb, Kpb, Vtb, nullptr, nullptr);
  attn_kernel<<<768, 256, 0, stream>>>(Qpb, Kpb, Vtb, Ctx);
  gemm_kernel<1><<<dim3(64, 6), 256, 0, stream>>>(Ctx, Wob, nullptr, nullptr, nullptr, bo, out);
}

// Round 10
// 150.817 us; speedup vs baseline: 1.1151x; 1.0569x over previous
//
#include <hip/hip_runtime.h>
#include <stdint.h>

#define TT 2048
#define DD 768
#define NHEAD 12
#define DH 64
#define MM 8192   // B*T
#define DP 80     // padded head dim (64 data + 6 bias + 10 zero)

typedef __attribute__((ext_vector_type(8))) short bf16x8;
typedef __attribute__((ext_vector_type(4))) float f32x4;
typedef __attribute__((ext_vector_type(16))) float f32x16;
typedef __attribute__((ext_vector_type(2))) unsigned int u32x2v;
typedef unsigned short u16;

#define GAS __attribute__((address_space(1)))
#define LAS __attribute__((address_space(3)))

static __device__ __forceinline__ void gload16(const void* g, void* l) {
  __builtin_amdgcn_global_load_lds((const GAS uint32_t*)g, (LAS uint32_t*)l, 16, 0, 0);
}

static __device__ __forceinline__ u16 f2b(float f) {
  union { float f; uint32_t u; } x; x.f = f;
  uint32_t r = x.u + 0x7fffu + ((x.u >> 16) & 1u);
  return (u16)(r >> 16);
}
static __device__ __forceinline__ float b2f(u16 v) {
  union { uint32_t u; float f; } x; x.u = ((uint32_t)v) << 16; return x.f;
}

#if __has_builtin(__builtin_amdgcn_exp2f)
#define EXP2(x) __builtin_amdgcn_exp2f(x)
#else
#define EXP2(x) exp2f(x)
#endif

static __device__ __forceinline__ void pswap(uint32_t& a, uint32_t& b) {
#if __has_builtin(__builtin_amdgcn_permlane32_swap)
  u32x2v r = __builtin_amdgcn_permlane32_swap(a, b, false, false);
  a = r[0]; b = r[1];
#else
  uint32_t ax = (uint32_t)__shfl_xor((int)a, 32, 64);
  uint32_t bx = (uint32_t)__shfl_xor((int)b, 32, 64);
  bool lo = (threadIdx.x & 32) == 0;
  uint32_t na = lo ? a : bx, nb = lo ? ax : b;
  a = na; b = nb;
#endif
}
static __device__ __forceinline__ uint32_t cvtpk(float lo, float hi_) {
  uint32_t r;
  asm("v_cvt_pk_bf16_f32 %0, %1, %2" : "=v"(r) : "v"(lo), "v"(hi_));
  return r;
}
static __device__ __forceinline__ f32x16 mfma32(bf16x8 a, bf16x8 b, f32x16 c) {
  return __builtin_amdgcn_mfma_f32_32x32x16_bf16(a, b, c, 0, 0, 0);
}

// ---------------- convert f32 -> bf16 (pure streaming) ----------------
__global__ __launch_bounds__(256) void convert_kernel(
    const float* __restrict__ H, const float* __restrict__ wq,
    const float* __restrict__ wk, const float* __restrict__ wv,
    const float* __restrict__ wo,
    u16* __restrict__ Hb, u16* __restrict__ Wqkv, u16* __restrict__ Wob) {
  const size_t NHEL = (size_t)MM * DD;
  const size_t NW = (size_t)DD * DD;
  size_t i = ((size_t)blockIdx.x * 256 + threadIdx.x) * 4;
  const float* src; u16* dst; size_t so, dofs;
  if (i < NHEL) { src = H; so = i; dst = Hb; dofs = i; }
  else if (i < NHEL + 3 * NW) {
    size_t j = i - NHEL; dst = Wqkv; dofs = j;
    if (j < NW) { src = wq; so = j; }
    else if (j < 2 * NW) { src = wk; so = j - NW; }
    else { src = wv; so = j - 2 * NW; }
  } else if (i < NHEL + 4 * NW) {
    size_t j = i - NHEL - 3 * NW; src = wo; so = j; dst = Wob; dofs = j;
  } else return;
  float4 v = *(const float4*)&src[so];
  ushort4 o;
  o.x = f2b(v.x); o.y = f2b(v.y); o.z = f2b(v.z); o.w = f2b(v.w);
  *(ushort4*)&dst[dofs] = o;
}

// ---------------- GEMM (MODE 0): QKV proj, 128x128 tile ----------------
// A=Hb, Bw=[wq;wk;wv] (N=2304). Epilogue restages C-tile in LDS and writes
// Q (DP-strided, *0.125*log2e), K (DP-strided), V TRANSPOSED (b,h,dh,t) with
// coalesced chunks. Bias dims 64..79 of Q/K rows are computed and written
// here too (each (token,head) row is owned by exactly one tile) -> every
// 160B row fully written by one block (streaming, no partial lines).
__global__ __launch_bounds__(256) void gemm0_kernel(
    const u16* __restrict__ A, const u16* __restrict__ Bw,
    u16* __restrict__ Qp, u16* __restrict__ Kp, u16* __restrict__ Vt,
    const float* __restrict__ Pp, const float* __restrict__ Sp,
    const float* __restrict__ compat, const float* __restrict__ gamma) {
  __shared__ u16 SMEM[17408];                 // As(8192) + Bs(8192); Ct overlays (128*136)
  u16* As = SMEM;
  u16* Bs = SMEM + 8192;
  const int tid = threadIdx.x;
  const int lane = tid & 63, w = tid >> 6;
  const int wr = w >> 1, wc = w & 1;
  const int g = lane >> 4, r = lane & 15;
  const int m0 = blockIdx.x * 128, n0 = blockIdx.y * 128;

  f32x4 acc[4][4];
#pragma unroll
  for (int m = 0; m < 4; ++m)
#pragma unroll
    for (int n = 0; n < 4; ++n) acc[m][n] = (f32x4){0.f, 0.f, 0.f, 0.f};

  for (int ks = 0; ks < 12; ++ks) {
    const int k0 = ks * 64;
    __syncthreads();
#pragma unroll
    for (int ii = 0; ii < 4; ++ii) {
      int seg = (w * 4 + ii) * 64 + lane;
      int row = seg >> 3, cs = seg & 7;
      int csw = cs ^ (row & 7);
      // each gload16 covers 64 lanes x 16B = 1024B = 512 u16 -> dest stride *512
      gload16(&A[(size_t)(m0 + row) * DD + k0 + csw * 8], &As[(w * 4 + ii) * 512]);
      gload16(&Bw[(size_t)(n0 + row) * DD + k0 + csw * 8], &Bs[(w * 4 + ii) * 512]);
    }
    __syncthreads();
#pragma unroll
    for (int kk = 0; kk < 2; ++kk) {
      bf16x8 af[4], bfr[4];
#pragma unroll
      for (int m = 0; m < 4; ++m) {
        int row = wr * 64 + m * 16 + r;
        int ch = (kk * 4 + g) ^ (row & 7);
        af[m] = *(const bf16x8*)&As[row * 64 + ch * 8];
      }
#pragma unroll
      for (int n = 0; n < 4; ++n) {
        int row = wc * 64 + n * 16 + r;
        int ch = (kk * 4 + g) ^ (row & 7);
        bfr[n] = *(const bf16x8*)&Bs[row * 64 + ch * 8];
      }
#pragma unroll
      for (int m = 0; m < 4; ++m)
#pragma unroll
        for (int n = 0; n < 4; ++n)
          acc[m][n] = __builtin_amdgcn_mfma_f32_16x16x32_bf16(af[m], bfr[n], acc[m][n], 0, 0, 0);
    }
  }

  const int sel = n0 / DD;            // 0=Q 1=K 2=V  (tiles never straddle)
  const int e0b = n0 - sel * DD;      // head-block base, h0 = e0b>>6
  const int bb = m0 >> 11;            // batch
  const int tb = m0 & (TT - 1);       // token base (multiple of 128)
  __syncthreads();                    // all LDS reads of As/Bs done
#pragma unroll
  for (int m = 0; m < 4; ++m) {
#pragma unroll
    for (int n = 0; n < 4; ++n) {
#pragma unroll
      for (int reg = 0; reg < 4; ++reg) {
        float v = acc[m][n][reg];
        int t = wr * 64 + m * 16 + g * 4 + reg;   // local token 0..127
        int c = wc * 64 + n * 16 + r;             // local N col 0..127
        u16 bv = f2b(sel == 0 ? v * 0.18033688f : v);  // Q: *0.125*log2(e)
        if (sel < 2) SMEM[t * 136 + c] = bv;      // Ct[t][c]
        else         SMEM[c * 136 + t] = bv;      // Ct[dh][t] (transposed)
      }
    }
  }
  __syncthreads();
  if (sel < 2) {
    u16* base = (sel == 0) ? Qp : Kp;
    const int grp = tid >> 3, li = tid & 7;       // 32 groups x 8 lanes
#pragma unroll
    for (int it = 0; it < 8; ++it) {
      int chunk = it * 32 + grp;                  // 0..255
      int t = chunk & 127, hh = chunk >> 7;
      int h = (e0b >> 6) + hh;
      size_t row = ((size_t)(bb * NHEAD + h) * TT + tb + t) * DP;
      uint4 d = *(const uint4*)&SMEM[t * 136 + hh * 64 + li * 8];
      *(uint4*)&base[row + li * 8] = d;
    }
    // ---- bias dims 64..79: one (t,hh) chunk per thread, 32B each ----
    {
      const float L2E = 1.44269504f;
      int t = tid & 127, hh = tid >> 7;
      int h = (e0b >> 6) + hh;
      size_t ip = (size_t)bb * TT + tb + t;
      float p0 = Pp[ip * 2], p1 = Pp[ip * 2 + 1];
      union { u16 u[8]; uint4 v; } bias;
      union { u16 u[8]; uint4 v; } zz;
#pragma unroll
      for (int z = 0; z < 8; ++z) zz.u[z] = 0;
      if (sel == 0) {
        float c00 = compat[h * 4 + 0], c01 = compat[h * 4 + 1];
        float c10 = compat[h * 4 + 2], c11 = compat[h * 4 + 3];
        u16 q0 = f2b((p0 * c00 + p1 * c10) * L2E);
        u16 q1 = f2b((p0 * c01 + p1 * c11) * L2E);
        u16 gmb = f2b(gamma[0] * L2E);
        bias.u[0] = q0; bias.u[1] = q0; bias.u[2] = q1; bias.u[3] = q1;
        bias.u[4] = gmb; bias.u[5] = gmb; bias.u[6] = 0; bias.u[7] = 0;
      } else {
        float sv = Sp[ip];
        u16 p0h = f2b(p0); u16 p0l = f2b(p0 - b2f(p0h));
        u16 p1h = f2b(p1); u16 p1l = f2b(p1 - b2f(p1h));
        u16 svh = f2b(sv); u16 svl = f2b(sv - b2f(svh));
        bias.u[0] = p0h; bias.u[1] = p0l; bias.u[2] = p1h; bias.u[3] = p1l;
        bias.u[4] = svh; bias.u[5] = svl; bias.u[6] = 0; bias.u[7] = 0;
      }
      size_t row = ((size_t)(bb * NHEAD + h) * TT + tb + t) * DP;
      *(uint4*)&base[row + 64] = bias.v;
      *(uint4*)&base[row + 72] = zz.v;
    }
  } else {
    const int grp = tid >> 4, li = tid & 15;      // 16 groups x 16 lanes
#pragma unroll
    for (int it = 0; it < 8; ++it) {
      int c = it * 16 + grp;                      // 0..127
      int h = (e0b >> 6) + (c >> 6), dh = c & 63;
      size_t row = ((size_t)(bb * NHEAD + h)) * DH * TT + (size_t)dh * TT + tb;
      uint4 d = *(const uint4*)&SMEM[c * 136 + li * 8];
      *(uint4*)&Vt[row + li * 8] = d;
    }
  }
}

// ---------------- GEMM (MODE 1): out-proj, 64x128 tile, 768 blocks (3/CU) ----
__global__ __launch_bounds__(256) void gemm1_kernel(
    const u16* __restrict__ A, const u16* __restrict__ Bw,
    const float* __restrict__ bo, float* __restrict__ Out) {
  __shared__ u16 SMEM[12288];                 // As 64x64 (4096) + Bs 128x64 (8192)
  u16* As = SMEM;
  u16* Bs = SMEM + 4096;
  const int tid = threadIdx.x;
  const int lane = tid & 63, w = tid >> 6;
  const int wr = w & 1, wc = w >> 1;          // wave: 32(M) x 64(N)
  const int g = lane >> 4, r = lane & 15;
  const int m0 = blockIdx.x * 64, n0 = blockIdx.y * 128;

  f32x4 acc[2][4];
#pragma unroll
  for (int m = 0; m < 2; ++m)
#pragma unroll
    for (int n = 0; n < 4; ++n) acc[m][n] = (f32x4){0.f, 0.f, 0.f, 0.f};

  for (int ks = 0; ks < 12; ++ks) {
    const int k0 = ks * 64;
    __syncthreads();
#pragma unroll
    for (int i = 0; i < 6; ++i) {             // 24 chunks over 4 waves
      int idx = w + 4 * i;
      if (idx < 8) {                          // A chunks 0..7 (64 rows)
        int n = idx * 64 + lane;
        int row = n >> 3, cs = n & 7;
        int csw = cs ^ (row & 7);
        gload16(&A[(size_t)(m0 + row) * DD + k0 + csw * 8], &As[idx * 512]);
      } else {                                // B chunks 0..15 (128 rows)
        int j = idx - 8;
        int n = j * 64 + lane;
        int row = n >> 3, cs = n & 7;
        int csw = cs ^ (row & 7);
        gload16(&Bw[(size_t)(n0 + row) * DD + k0 + csw * 8], &Bs[j * 512]);
      }
    }
    __syncthreads();
#pragma unroll
    for (int kk = 0; kk < 2; ++kk) {
      bf16x8 af[2], bfr[4];
#pragma unroll
      for (int m = 0; m < 2; ++m) {
        int row = wr * 32 + m * 16 + r;
        int ch = (kk * 4 + g) ^ (row & 7);
        af[m] = *(const bf16x8*)&As[row * 64 + ch * 8];
      }
#pragma unroll
      for (int n = 0; n < 4; ++n) {
        int row = wc * 64 + n * 16 + r;
        int ch = (kk * 4 + g) ^ (row & 7);
        bfr[n] = *(const bf16x8*)&Bs[row * 64 + ch * 8];
      }
#pragma unroll
      for (int m = 0; m < 2; ++m)
#pragma unroll
        for (int n = 0; n < 4; ++n)
          acc[m][n] = __builtin_amdgcn_mfma_f32_16x16x32_bf16(af[m], bfr[n], acc[m][n], 0, 0, 0);
    }
  }

#pragma unroll
  for (int m = 0; m < 2; ++m) {
#pragma unroll
    for (int n = 0; n < 4; ++n) {
#pragma unroll
      for (int reg = 0; reg < 4; ++reg) {
        int gt = m0 + wr * 32 + m * 16 + g * 4 + reg;
        int e = n0 + wc * 64 + n * 16 + r;
        Out[(size_t)gt * DD + e] = acc[m][n][reg] + bo[e];
      }
    }
  }
}

// ---------------- attention: swapped QK^T, fixed-base softmax (m=0), l via MFMA ----------------
// R4-proven structure: 4 waves x 32 q, full 64-key tile per wave, single
// barrier per tile, K/V double-buffered via global_load_lds.
#define QB 128
__global__ __launch_bounds__(256, 3) void attn_kernel(
    const u16* __restrict__ Qp, const u16* __restrict__ Kp, const u16* __restrict__ Vtb,
    u16* __restrict__ Ctx) {
  __shared__ u16 Ks[2][64 * 88];   // 64 rows x 176B (160B data + 16B pad-dup)
  __shared__ u16 Vs[2][64 * 64];   // [dh][key], source pre-swizzled
  const int tid = threadIdx.x, lane = tid & 63, w = tid >> 6;
  const int hi = lane >> 5, ql = lane & 31;
  const int bid = blockIdx.x;
  const int bh = bid % 48, qb = bid / 48;   // bh-major: same bh -> same XCD
  const int b = bh / NHEAD, h = bh % NHEAD;

  const char* KgB = (const char*)(Kp + (size_t)bh * TT * DP);
  const char* VgB = (const char*)(Vtb + (size_t)bh * DH * TT);
  const u16* Qg = Qp + (size_t)bh * TT * DP;

  const int q = qb * QB + w * 32 + ql;
  bf16x8 Qf[5];
#pragma unroll
  for (int kbl = 0; kbl < 5; ++kbl)
    Qf[kbl] = *(const bf16x8*)&Qg[(size_t)q * DP + (2 * kbl + hi) * 8];

  union { u16 u[8]; bf16x8 v; } ones;
#pragma unroll
  for (int z = 0; z < 8; ++z) ones.u[z] = 0x3F80;  // bf16 1.0

  auto kofs = [&](int i) {
    int n = i * 64 + lane;
    int rr = (n * 2979) >> 15;       // n/11 exact for n<768
    int c = n - 11 * rr; if (c > 9) c = 9;
    return rr * 160 + c * 16;
  };
  auto vofs = [&](int j) {
    int n = j * 64 + lane;
    int dh = n >> 3, cs = n & 7;
    return dh * 4096 + (cs ^ (dh & 7)) * 16;
  };
  const int koff0 = kofs(w), koff1 = kofs(w + 4), koff2 = (w < 3) ? kofs(w + 8) : 0;
  const int voff0 = vofs(w), voff1 = vofs(w + 4);

  auto STAGE = [&](int nb, int t0) {
    const char* ksrc = KgB + (size_t)t0 * 160;
    char* kd = (char*)&Ks[nb][0];
    gload16(ksrc + koff0, kd + w * 1024);
    gload16(ksrc + koff1, kd + (w + 4) * 1024);
    if (w < 3) gload16(ksrc + koff2, kd + (w + 8) * 1024);
    const char* vsrc = VgB + (size_t)t0 * 2;
    char* vd = (char*)&Vs[nb][0];
    gload16(vsrc + voff0, vd + w * 1024);
    gload16(vsrc + voff1, vd + (w + 4) * 1024);
  };

  f32x16 o0, o1, ol;
#pragma unroll
  for (int z = 0; z < 16; ++z) { o0[z] = 0.f; o1[z] = 0.f; ol[z] = 0.f; }

  STAGE(0, 0);

  for (int kt = 0; kt < 32; ++kt) {
    __syncthreads();                       // drains vmcnt: current buffers valid
    if (kt + 1 < 32) STAGE((kt + 1) & 1, (kt + 1) * 64);
    const u16* Kb_ = &Ks[kt & 1][0];
    const u16* Vb_ = &Vs[kt & 1][0];

    // S^T = K' * Q'^T : rows=keys, cols=q (lane&31). Two 32-key blocks.
    f32x16 s0, s1;
#pragma unroll
    for (int z = 0; z < 16; ++z) { s0[z] = 0.f; s1[z] = 0.f; }
    __builtin_amdgcn_s_setprio(1);
#pragma unroll
    for (int kbl = 0; kbl < 5; ++kbl) {
      bf16x8 a0 = *(const bf16x8*)&Kb_[ql * 88 + hi * 8 + kbl * 16];
      s0 = mfma32(a0, Qf[kbl], s0);
    }
#pragma unroll
    for (int kbl = 0; kbl < 5; ++kbl) {
      bf16x8 a1 = *(const bf16x8*)&Kb_[(ql + 32) * 88 + hi * 8 + kbl * 16];
      s1 = mfma32(a1, Qf[kbl], s1);
    }
    __builtin_amdgcn_s_setprio(0);

    // P = exp2(S) directly (fixed base m=0)
    float p_[32];
#pragma unroll
    for (int z = 0; z < 16; ++z) p_[z] = EXP2(s0[z]);
#pragma unroll
    for (int z = 0; z < 16; ++z) p_[16 + z] = EXP2(s1[z]);

    // build PA fragments in-register (cvt_pk + permlane32_swap); PV + l-column
    __builtin_amdgcn_s_setprio(1);
#pragma unroll
    for (int ks = 0; ks < 4; ++ks) {
      const int base = ks * 8;
      uint32_t wa = cvtpk(p_[base + 0], p_[base + 1]);
      uint32_t wb = cvtpk(p_[base + 4], p_[base + 5]);
      uint32_t wc = cvtpk(p_[base + 2], p_[base + 3]);
      uint32_t wd = cvtpk(p_[base + 6], p_[base + 7]);
      pswap(wa, wb);
      pswap(wc, wd);
      union { uint32_t u[4]; bf16x8 v; } pa;
      pa.u[0] = wa; pa.u[1] = wc; pa.u[2] = wb; pa.u[3] = wd;
#pragma unroll
      for (int nb = 0; nb < 2; ++nb) {
        int row = ql + 32 * nb;
        bf16x8 vf = *(const bf16x8*)&Vb_[row * 64 + (((2 * ks + hi) ^ (ql & 7)) * 8)];
        if (nb == 0) o0 = mfma32(pa.v, vf, o0);
        else         o1 = mfma32(pa.v, vf, o1);
      }
      ol = mfma32(pa.v, ones.v, ol);       // row-sum of P (all cols identical)
    }
    __builtin_amdgcn_s_setprio(0);
  }

  // epilogue: l is in-register in the same row layout as o0/o1 — no broadcast
#pragma unroll
  for (int z = 0; z < 16; ++z) {
    int q2 = (z & 3) + 8 * (z >> 2) + 4 * hi;
    float il = 1.0f / ol[z];
    int qrow = qb * QB + w * 32 + q2;
    size_t rowb = ((size_t)b * TT + qrow) * DD + h * DH;
    Ctx[rowb + ql]      = f2b(o0[z] * il);
    Ctx[rowb + ql + 32] = f2b(o1[z] * il);
  }
}

extern "C" void kernel_launch(void* const* d_in, const int* in_sizes, int n_in,
                              void* d_out, int out_size, void* d_ws, size_t ws_size,
                              hipStream_t stream) {
  const float* H = (const float*)d_in[0];
  const float* p = (const float*)d_in[1];
  const float* s = (const float*)d_in[2];
  const float* wq = (const float*)d_in[3];
  const float* wk = (const float*)d_in[4];
  const float* wv = (const float*)d_in[5];
  const float* wo = (const float*)d_in[6];
  const float* bo = (const float*)d_in[7];
  const float* compat = (const float*)d_in[8];
  const float* gamma = (const float*)d_in[9];
  float* out = (float*)d_out;

  char* ws = (char*)d_ws;
  u16* Hb   = (u16*)(ws);               // 12,582,912 B (dead after gemm0 -> Ctx)
  u16* Wqkv = (u16*)(ws + 12582912);    //  3,538,944 B
  u16* Wob  = (u16*)(ws + 16121856);    //  1,179,648 B
  u16* Qpb  = (u16*)(ws + 17301504);    // 15,728,640 B  (B*H*T*80 bf16)
  u16* Kpb  = (u16*)(ws + 33030144);    // 15,728,640 B
  u16* Vtb  = (u16*)(ws + 48758784);    // 12,582,912 B  (written transposed by gemm0)
  u16* Ctx  = Hb;                       // alias: Hb dead after gemm0
  // total 61,341,696 B

  convert_kernel<<<8448, 256, 0, stream>>>(H, wq, wk, wv, wo, Hb, Wqkv, Wob);
  gemm0_kernel<<<dim3(64, 18), 256, 0, stream>>>(Hb, Wqkv, Qpb, Kpb, Vtb, p, s, compat, gamma);
  attn_kernel<<<768, 256, 0, stream>>>(Qpb, Kpb, Vtb, Ctx);
  gemm1_kernel<<<dim3(128, 6), 256, 0, stream>>>(Ctx, Wob, bo, out);
}

// Round 11
// 150.182 us; speedup vs baseline: 1.1198x; 1.0042x over previous
//
#include <hip/hip_runtime.h>
#include <stdint.h>

#define TT 2048
#define DD 768
#define NHEAD 12
#define DH 64
#define MM 8192   // B*T
#define DP 80     // padded head dim (64 data + 6 bias + 10 zero)

typedef __attribute__((ext_vector_type(8))) short bf16x8;
typedef __attribute__((ext_vector_type(4))) float f32x4;
typedef __attribute__((ext_vector_type(16))) float f32x16;
typedef __attribute__((ext_vector_type(2))) unsigned int u32x2v;
typedef unsigned short u16;

#define GAS __attribute__((address_space(1)))
#define LAS __attribute__((address_space(3)))

static __device__ __forceinline__ void gload16(const void* g, void* l) {
  __builtin_amdgcn_global_load_lds((const GAS uint32_t*)g, (LAS uint32_t*)l, 16, 0, 0);
}

static __device__ __forceinline__ u16 f2b(float f) {
  union { float f; uint32_t u; } x; x.f = f;
  uint32_t r = x.u + 0x7fffu + ((x.u >> 16) & 1u);
  return (u16)(r >> 16);
}
static __device__ __forceinline__ float b2f(u16 v) {
  union { uint32_t u; float f; } x; x.u = ((uint32_t)v) << 16; return x.f;
}

#if __has_builtin(__builtin_amdgcn_exp2f)
#define EXP2(x) __builtin_amdgcn_exp2f(x)
#else
#define EXP2(x) exp2f(x)
#endif

static __device__ __forceinline__ void pswap(uint32_t& a, uint32_t& b) {
#if __has_builtin(__builtin_amdgcn_permlane32_swap)
  u32x2v r = __builtin_amdgcn_permlane32_swap(a, b, false, false);
  a = r[0]; b = r[1];
#else
  uint32_t ax = (uint32_t)__shfl_xor((int)a, 32, 64);
  uint32_t bx = (uint32_t)__shfl_xor((int)b, 32, 64);
  bool lo = (threadIdx.x & 32) == 0;
  uint32_t na = lo ? a : bx, nb = lo ? ax : b;
  a = na; b = nb;
#endif
}
static __device__ __forceinline__ uint32_t cvtpk(float lo, float hi_) {
  uint32_t r;
  asm("v_cvt_pk_bf16_f32 %0, %1, %2" : "=v"(r) : "v"(lo), "v"(hi_));
  return r;
}
static __device__ __forceinline__ f32x16 mfma32(bf16x8 a, bf16x8 b, f32x16 c) {
  return __builtin_amdgcn_mfma_f32_32x32x16_bf16(a, b, c, 0, 0, 0);
}

// ---------------- convert f32 -> bf16 (pure streaming, 8 el/thread) ----------------
__global__ __launch_bounds__(256) void convert_kernel(
    const float* __restrict__ H, const float* __restrict__ wq,
    const float* __restrict__ wk, const float* __restrict__ wv,
    const float* __restrict__ wo,
    u16* __restrict__ Hb, u16* __restrict__ Wqkv, u16* __restrict__ Wob) {
  const size_t NHEL = (size_t)MM * DD;     // 6291456 (mult of 8)
  const size_t NW = (size_t)DD * DD;       // 589824  (mult of 8)
  size_t i = ((size_t)blockIdx.x * 256 + threadIdx.x) * 8;
  const float* src; u16* dst; size_t so, dofs;
  if (i < NHEL) { src = H; so = i; dst = Hb; dofs = i; }
  else if (i < NHEL + 3 * NW) {
    size_t j = i - NHEL; dst = Wqkv; dofs = j;
    if (j < NW) { src = wq; so = j; }
    else if (j < 2 * NW) { src = wk; so = j - NW; }
    else { src = wv; so = j - 2 * NW; }
  } else if (i < NHEL + 4 * NW) {
    size_t j = i - NHEL - 3 * NW; src = wo; so = j; dst = Wob; dofs = j;
  } else return;
  float4 v0 = *(const float4*)&src[so];
  float4 v1 = *(const float4*)&src[so + 4];
  union { u16 u[8]; uint4 v; } o;
  o.u[0] = f2b(v0.x); o.u[1] = f2b(v0.y); o.u[2] = f2b(v0.z); o.u[3] = f2b(v0.w);
  o.u[4] = f2b(v1.x); o.u[5] = f2b(v1.y); o.u[6] = f2b(v1.z); o.u[7] = f2b(v1.w);
  *(uint4*)&dst[dofs] = o.v;
}

// ---------------- GEMM (MODE 0): QKV proj, 128x128 tile, XCD-swizzled grid ----------------
// Grid = 1152 linear blocks. swz = (lin%8)*144 + lin/8 (m204 bijective for
// nwg%8==0): XCD k owns M-stripes [8k,8k+8) with n fastest -> concurrent
// working set = 2 A-panels + 18 B-panels ~ 3.9 MB, L2-resident per XCD.
// Epilogue restages C-tile in LDS and writes Q (DP-strided, *0.125*log2e),
// K (DP-strided), V TRANSPOSED (b,h,dh,t), + bias dims 64..79 for Q/K.
__global__ __launch_bounds__(256) void gemm0_kernel(
    const u16* __restrict__ A, const u16* __restrict__ Bw,
    u16* __restrict__ Qp, u16* __restrict__ Kp, u16* __restrict__ Vt,
    const float* __restrict__ Pp, const float* __restrict__ Sp,
    const float* __restrict__ compat, const float* __restrict__ gamma) {
  __shared__ u16 SMEM[17408];                 // As(8192) + Bs(8192); Ct overlays (128*136)
  u16* As = SMEM;
  u16* Bs = SMEM + 8192;
  const int tid = threadIdx.x;
  const int lane = tid & 63, w = tid >> 6;
  const int wr = w >> 1, wc = w & 1;
  const int g = lane >> 4, r = lane & 15;
  const int lin = blockIdx.x;
  const int swz = (lin & 7) * 144 + (lin >> 3);
  const int m0 = (swz / 18) * 128, n0 = (swz % 18) * 128;

  f32x4 acc[4][4];
#pragma unroll
  for (int m = 0; m < 4; ++m)
#pragma unroll
    for (int n = 0; n < 4; ++n) acc[m][n] = (f32x4){0.f, 0.f, 0.f, 0.f};

  for (int ks = 0; ks < 12; ++ks) {
    const int k0 = ks * 64;
    __syncthreads();
#pragma unroll
    for (int ii = 0; ii < 4; ++ii) {
      int seg = (w * 4 + ii) * 64 + lane;
      int row = seg >> 3, cs = seg & 7;
      int csw = cs ^ (row & 7);
      // each gload16 covers 64 lanes x 16B = 1024B = 512 u16 -> dest stride *512
      gload16(&A[(size_t)(m0 + row) * DD + k0 + csw * 8], &As[(w * 4 + ii) * 512]);
      gload16(&Bw[(size_t)(n0 + row) * DD + k0 + csw * 8], &Bs[(w * 4 + ii) * 512]);
    }
    __syncthreads();
#pragma unroll
    for (int kk = 0; kk < 2; ++kk) {
      bf16x8 af[4], bfr[4];
#pragma unroll
      for (int m = 0; m < 4; ++m) {
        int row = wr * 64 + m * 16 + r;
        int ch = (kk * 4 + g) ^ (row & 7);
        af[m] = *(const bf16x8*)&As[row * 64 + ch * 8];
      }
#pragma unroll
      for (int n = 0; n < 4; ++n) {
        int row = wc * 64 + n * 16 + r;
        int ch = (kk * 4 + g) ^ (row & 7);
        bfr[n] = *(const bf16x8*)&Bs[row * 64 + ch * 8];
      }
#pragma unroll
      for (int m = 0; m < 4; ++m)
#pragma unroll
        for (int n = 0; n < 4; ++n)
          acc[m][n] = __builtin_amdgcn_mfma_f32_16x16x32_bf16(af[m], bfr[n], acc[m][n], 0, 0, 0);
    }
  }

  const int sel = n0 / DD;            // 0=Q 1=K 2=V  (tiles never straddle)
  const int e0b = n0 - sel * DD;      // head-block base, h0 = e0b>>6
  const int bb = m0 >> 11;            // batch
  const int tb = m0 & (TT - 1);       // token base (multiple of 128)
  __syncthreads();                    // all LDS reads of As/Bs done
#pragma unroll
  for (int m = 0; m < 4; ++m) {
#pragma unroll
    for (int n = 0; n < 4; ++n) {
#pragma unroll
      for (int reg = 0; reg < 4; ++reg) {
        float v = acc[m][n][reg];
        int t = wr * 64 + m * 16 + g * 4 + reg;   // local token 0..127
        int c = wc * 64 + n * 16 + r;             // local N col 0..127
        u16 bv = f2b(sel == 0 ? v * 0.18033688f : v);  // Q: *0.125*log2(e)
        if (sel < 2) SMEM[t * 136 + c] = bv;      // Ct[t][c]
        else         SMEM[c * 136 + t] = bv;      // Ct[dh][t] (transposed)
      }
    }
  }
  __syncthreads();
  if (sel < 2) {
    u16* base = (sel == 0) ? Qp : Kp;
    const int grp = tid >> 3, li = tid & 7;       // 32 groups x 8 lanes
#pragma unroll
    for (int it = 0; it < 8; ++it) {
      int chunk = it * 32 + grp;                  // 0..255
      int t = chunk & 127, hh = chunk >> 7;
      int h = (e0b >> 6) + hh;
      size_t row = ((size_t)(bb * NHEAD + h) * TT + tb + t) * DP;
      uint4 d = *(const uint4*)&SMEM[t * 136 + hh * 64 + li * 8];
      *(uint4*)&base[row + li * 8] = d;
    }
    // ---- bias dims 64..79: one (t,hh) chunk per thread, 32B each ----
    {
      const float L2E = 1.44269504f;
      int t = tid & 127, hh = tid >> 7;
      int h = (e0b >> 6) + hh;
      size_t ip = (size_t)bb * TT + tb + t;
      float p0 = Pp[ip * 2], p1 = Pp[ip * 2 + 1];
      union { u16 u[8]; uint4 v; } bias;
      union { u16 u[8]; uint4 v; } zz;
#pragma unroll
      for (int z = 0; z < 8; ++z) zz.u[z] = 0;
      if (sel == 0) {
        float c00 = compat[h * 4 + 0], c01 = compat[h * 4 + 1];
        float c10 = compat[h * 4 + 2], c11 = compat[h * 4 + 3];
        u16 q0 = f2b((p0 * c00 + p1 * c10) * L2E);
        u16 q1 = f2b((p0 * c01 + p1 * c11) * L2E);
        u16 gmb = f2b(gamma[0] * L2E);
        bias.u[0] = q0; bias.u[1] = q0; bias.u[2] = q1; bias.u[3] = q1;
        bias.u[4] = gmb; bias.u[5] = gmb; bias.u[6] = 0; bias.u[7] = 0;
      } else {
        float sv = Sp[ip];
        u16 p0h = f2b(p0); u16 p0l = f2b(p0 - b2f(p0h));
        u16 p1h = f2b(p1); u16 p1l = f2b(p1 - b2f(p1h));
        u16 svh = f2b(sv); u16 svl = f2b(sv - b2f(svh));
        bias.u[0] = p0h; bias.u[1] = p0l; bias.u[2] = p1h; bias.u[3] = p1l;
        bias.u[4] = svh; bias.u[5] = svl; bias.u[6] = 0; bias.u[7] = 0;
      }
      size_t row = ((size_t)(bb * NHEAD + h) * TT + tb + t) * DP;
      *(uint4*)&base[row + 64] = bias.v;
      *(uint4*)&base[row + 72] = zz.v;
    }
  } else {
    const int grp = tid >> 4, li = tid & 15;      // 16 groups x 16 lanes
#pragma unroll
    for (int it = 0; it < 8; ++it) {
      int c = it * 16 + grp;                      // 0..127
      int h = (e0b >> 6) + (c >> 6), dh = c & 63;
      size_t row = ((size_t)(bb * NHEAD + h)) * DH * TT + (size_t)dh * TT + tb;
      uint4 d = *(const uint4*)&SMEM[c * 136 + li * 8];
      *(uint4*)&Vt[row + li * 8] = d;
    }
  }
}

// ---------------- GEMM (MODE 1): out-proj, 64x128 tile, 768 blocks (3/CU) ----
__global__ __launch_bounds__(256) void gemm1_kernel(
    const u16* __restrict__ A, const u16* __restrict__ Bw,
    const float* __restrict__ bo, float* __restrict__ Out) {
  __shared__ u16 SMEM[12288];                 // As 64x64 (4096) + Bs 128x64 (8192)
  u16* As = SMEM;
  u16* Bs = SMEM + 4096;
  const int tid = threadIdx.x;
  const int lane = tid & 63, w = tid >> 6;
  const int wr = w & 1, wc = w >> 1;          // wave: 32(M) x 64(N)
  const int g = lane >> 4, r = lane & 15;
  const int m0 = blockIdx.x * 64, n0 = blockIdx.y * 128;

  f32x4 acc[2][4];
#pragma unroll
  for (int m = 0; m < 2; ++m)
#pragma unroll
    for (int n = 0; n < 4; ++n) acc[m][n] = (f32x4){0.f, 0.f, 0.f, 0.f};

  for (int ks = 0; ks < 12; ++ks) {
    const int k0 = ks * 64;
    __syncthreads();
#pragma unroll
    for (int i = 0; i < 6; ++i) {             // 24 chunks over 4 waves
      int idx = w + 4 * i;
      if (idx < 8) {                          // A chunks 0..7 (64 rows)
        int n = idx * 64 + lane;
        int row = n >> 3, cs = n & 7;
        int csw = cs ^ (row & 7);
        gload16(&A[(size_t)(m0 + row) * DD + k0 + csw * 8], &As[idx * 512]);
      } else {                                // B chunks 0..15 (128 rows)
        int j = idx - 8;
        int n = j * 64 + lane;
        int row = n >> 3, cs = n & 7;
        int csw = cs ^ (row & 7);
        gload16(&Bw[(size_t)(n0 + row) * DD + k0 + csw * 8], &Bs[j * 512]);
      }
    }
    __syncthreads();
#pragma unroll
    for (int kk = 0; kk < 2; ++kk) {
      bf16x8 af[2], bfr[4];
#pragma unroll
      for (int m = 0; m < 2; ++m) {
        int row = wr * 32 + m * 16 + r;
        int ch = (kk * 4 + g) ^ (row & 7);
        af[m] = *(const bf16x8*)&As[row * 64 + ch * 8];
      }
#pragma unroll
      for (int n = 0; n < 4; ++n) {
        int row = wc * 64 + n * 16 + r;
        int ch = (kk * 4 + g) ^ (row & 7);
        bfr[n] = *(const bf16x8*)&Bs[row * 64 + ch * 8];
      }
#pragma unroll
      for (int m = 0; m < 2; ++m)
#pragma unroll
        for (int n = 0; n < 4; ++n)
          acc[m][n] = __builtin_amdgcn_mfma_f32_16x16x32_bf16(af[m], bfr[n], acc[m][n], 0, 0, 0);
    }
  }

#pragma unroll
  for (int m = 0; m < 2; ++m) {
#pragma unroll
    for (int n = 0; n < 4; ++n) {
#pragma unroll
      for (int reg = 0; reg < 4; ++reg) {
        int gt = m0 + wr * 32 + m * 16 + g * 4 + reg;
        int e = n0 + wc * 64 + n * 16 + r;
        Out[(size_t)gt * DD + e] = acc[m][n][reg] + bo[e];
      }
    }
  }
}

// ---------------- attention: swapped QK^T, fixed-base softmax (m=0), l via MFMA ----------------
// R4-proven structure: 4 waves x 32 q, full 64-key tile per wave, single
// barrier per tile, K/V double-buffered via global_load_lds.
#define QB 128
__global__ __launch_bounds__(256, 3) void attn_kernel(
    const u16* __restrict__ Qp, const u16* __restrict__ Kp, const u16* __restrict__ Vtb,
    u16* __restrict__ Ctx) {
  __shared__ u16 Ks[2][64 * 88];   // 64 rows x 176B (160B data + 16B pad-dup)
  __shared__ u16 Vs[2][64 * 64];   // [dh][key], source pre-swizzled
  const int tid = threadIdx.x, lane = tid & 63, w = tid >> 6;
  const int hi = lane >> 5, ql = lane & 31;
  const int bid = blockIdx.x;
  const int bh = bid % 48, qb = bid / 48;   // bh-major: same bh -> same XCD
  const int b = bh / NHEAD, h = bh % NHEAD;

  const char* KgB = (const char*)(Kp + (size_t)bh * TT * DP);
  const char* VgB = (const char*)(Vtb + (size_t)bh * DH * TT);
  const u16* Qg = Qp + (size_t)bh * TT * DP;

  const int q = qb * QB + w * 32 + ql;
  bf16x8 Qf[5];
#pragma unroll
  for (int kbl = 0; kbl < 5; ++kbl)
    Qf[kbl] = *(const bf16x8*)&Qg[(size_t)q * DP + (2 * kbl + hi) * 8];

  union { u16 u[8]; bf16x8 v; } ones;
#pragma unroll
  for (int z = 0; z < 8; ++z) ones.u[z] = 0x3F80;  // bf16 1.0

  auto kofs = [&](int i) {
    int n = i * 64 + lane;
    int rr = (n * 2979) >> 15;       // n/11 exact for n<768
    int c = n - 11 * rr; if (c > 9) c = 9;
    return rr * 160 + c * 16;
  };
  auto vofs = [&](int j) {
    int n = j * 64 + lane;
    int dh = n >> 3, cs = n & 7;
    return dh * 4096 + (cs ^ (dh & 7)) * 16;
  };
  const int koff0 = kofs(w), koff1 = kofs(w + 4), koff2 = (w < 3) ? kofs(w + 8) : 0;
  const int voff0 = vofs(w), voff1 = vofs(w + 4);

  auto STAGE = [&](int nb, int t0) {
    const char* ksrc = KgB + (size_t)t0 * 160;
    char* kd = (char*)&Ks[nb][0];
    gload16(ksrc + koff0, kd + w * 1024);
    gload16(ksrc + koff1, kd + (w + 4) * 1024);
    if (w < 3) gload16(ksrc + koff2, kd + (w + 8) * 1024);
    const char* vsrc = VgB + (size_t)t0 * 2;
    char* vd = (char*)&Vs[nb][0];
    gload16(vsrc + voff0, vd + w * 1024);
    gload16(vsrc + voff1, vd + (w + 4) * 1024);
  };

  f32x16 o0, o1, ol;
#pragma unroll
  for (int z = 0; z < 16; ++z) { o0[z] = 0.f; o1[z] = 0.f; ol[z] = 0.f; }

  STAGE(0, 0);

  for (int kt = 0; kt < 32; ++kt) {
    __syncthreads();                       // drains vmcnt: current buffers valid
    if (kt + 1 < 32) STAGE((kt + 1) & 1, (kt + 1) * 64);
    const u16* Kb_ = &Ks[kt & 1][0];
    const u16* Vb_ = &Vs[kt & 1][0];

    // S^T = K' * Q'^T : rows=keys, cols=q (lane&31). Two 32-key blocks.
    f32x16 s0, s1;
#pragma unroll
    for (int z = 0; z < 16; ++z) { s0[z] = 0.f; s1[z] = 0.f; }
    __builtin_amdgcn_s_setprio(1);
#pragma unroll
    for (int kbl = 0; kbl < 5; ++kbl) {
      bf16x8 a0 = *(const bf16x8*)&Kb_[ql * 88 + hi * 8 + kbl * 16];
      s0 = mfma32(a0, Qf[kbl], s0);
    }
#pragma unroll
    for (int kbl = 0; kbl < 5; ++kbl) {
      bf16x8 a1 = *(const bf16x8*)&Kb_[(ql + 32) * 88 + hi * 8 + kbl * 16];
      s1 = mfma32(a1, Qf[kbl], s1);
    }
    __builtin_amdgcn_s_setprio(0);

    // P = exp2(S) directly (fixed base m=0)
    float p_[32];
#pragma unroll
    for (int z = 0; z < 16; ++z) p_[z] = EXP2(s0[z]);
#pragma unroll
    for (int z = 0; z < 16; ++z) p_[16 + z] = EXP2(s1[z]);

    // build PA fragments in-register (cvt_pk + permlane32_swap); PV + l-column
    __builtin_amdgcn_s_setprio(1);
#pragma unroll
    for (int ks = 0; ks < 4; ++ks) {
      const int base = ks * 8;
      uint32_t wa = cvtpk(p_[base + 0], p_[base + 1]);
      uint32_t wb = cvtpk(p_[base + 4], p_[base + 5]);
      uint32_t wc = cvtpk(p_[base + 2], p_[base + 3]);
      uint32_t wd = cvtpk(p_[base + 6], p_[base + 7]);
      pswap(wa, wb);
      pswap(wc, wd);
      union { uint32_t u[4]; bf16x8 v; } pa;
      pa.u[0] = wa; pa.u[1] = wc; pa.u[2] = wb; pa.u[3] = wd;
#pragma unroll
      for (int nb = 0; nb < 2; ++nb) {
        int row = ql + 32 * nb;
        bf16x8 vf = *(const bf16x8*)&Vb_[row * 64 + (((2 * ks + hi) ^ (ql & 7)) * 8)];
        if (nb == 0) o0 = mfma32(pa.v, vf, o0);
        else         o1 = mfma32(pa.v, vf, o1);
      }
      ol = mfma32(pa.v, ones.v, ol);       // row-sum of P (all cols identical)
    }
    __builtin_amdgcn_s_setprio(0);
  }

  // epilogue: l is in-register in the same row layout as o0/o1 — no broadcast
#pragma unroll
  for (int z = 0; z < 16; ++z) {
    int q2 = (z & 3) + 8 * (z >> 2) + 4 * hi;
    float il = 1.0f / ol[z];
    int qrow = qb * QB + w * 32 + q2;
    size_t rowb = ((size_t)b * TT + qrow) * DD + h * DH;
    Ctx[rowb + ql]      = f2b(o0[z] * il);
    Ctx[rowb + ql + 32] = f2b(o1[z] * il);
  }
}

extern "C" void kernel_launch(void* const* d_in, const int* in_sizes, int n_in,
                              void* d_out, int out_size, void* d_ws, size_t ws_size,
                              hipStream_t stream) {
  const float* H = (const float*)d_in[0];
  const float* p = (const float*)d_in[1];
  const float* s = (const float*)d_in[2];
  const float* wq = (const float*)d_in[3];
  const float* wk = (const float*)d_in[4];
  const float* wv = (const float*)d_in[5];
  const float* wo = (const float*)d_in[6];
  const float* bo = (const float*)d_in[7];
  const float* compat = (const float*)d_in[8];
  const float* gamma = (const float*)d_in[9];
  float* out = (float*)d_out;

  char* ws = (char*)d_ws;
  u16* Hb   = (u16*)(ws);               // 12,582,912 B (dead after gemm0 -> Ctx)
  u16* Wqkv = (u16*)(ws + 12582912);    //  3,538,944 B
  u16* Wob  = (u16*)(ws + 16121856);    //  1,179,648 B
  u16* Qpb  = (u16*)(ws + 17301504);    // 15,728,640 B  (B*H*T*80 bf16)
  u16* Kpb  = (u16*)(ws + 33030144);    // 15,728,640 B
  u16* Vtb  = (u16*)(ws + 48758784);    // 12,582,912 B  (written transposed by gemm0)
  u16* Ctx  = Hb;                       // alias: Hb dead after gemm0
  // total 61,341,696 B

  convert_kernel<<<4224, 256, 0, stream>>>(H, wq, wk, wv, wo, Hb, Wqkv, Wob);
  gemm0_kernel<<<1152, 256, 0, stream>>>(Hb, Wqkv, Qpb, Kpb, Vtb, p, s, compat, gamma);
  attn_kernel<<<768, 256, 0, stream>>>(Qpb, Kpb, Vtb, Ctx);
  gemm1_kernel<<<dim3(128, 6), 256, 0, stream>>>(Ctx, Wob, bo, out);
}

// Round 12
// 148.219 us; speedup vs baseline: 1.1346x; 1.0132x over previous
//
#include <hip/hip_runtime.h>
#include <stdint.h>

#define TT 2048
#define DD 768
#define NHEAD 12
#define DH 64
#define MM 8192   // B*T
#define DP 80     // padded head dim (64 data + 6 bias + 10 zero)

typedef __attribute__((ext_vector_type(8))) short bf16x8;
typedef __attribute__((ext_vector_type(4))) float f32x4;
typedef __attribute__((ext_vector_type(16))) float f32x16;
typedef __attribute__((ext_vector_type(2))) unsigned int u32x2v;
typedef unsigned short u16;

#define GAS __attribute__((address_space(1)))
#define LAS __attribute__((address_space(3)))

static __device__ __forceinline__ void gload16(const void* g, void* l) {
  __builtin_amdgcn_global_load_lds((const GAS uint32_t*)g, (LAS uint32_t*)l, 16, 0, 0);
}

static __device__ __forceinline__ u16 f2b(float f) {
  union { float f; uint32_t u; } x; x.f = f;
  uint32_t r = x.u + 0x7fffu + ((x.u >> 16) & 1u);
  return (u16)(r >> 16);
}
static __device__ __forceinline__ float b2f(u16 v) {
  union { uint32_t u; float f; } x; x.u = ((uint32_t)v) << 16; return x.f;
}

#if __has_builtin(__builtin_amdgcn_exp2f)
#define EXP2(x) __builtin_amdgcn_exp2f(x)
#else
#define EXP2(x) exp2f(x)
#endif

static __device__ __forceinline__ void pswap(uint32_t& a, uint32_t& b) {
#if __has_builtin(__builtin_amdgcn_permlane32_swap)
  u32x2v r = __builtin_amdgcn_permlane32_swap(a, b, false, false);
  a = r[0]; b = r[1];
#else
  uint32_t ax = (uint32_t)__shfl_xor((int)a, 32, 64);
  uint32_t bx = (uint32_t)__shfl_xor((int)b, 32, 64);
  bool lo = (threadIdx.x & 32) == 0;
  uint32_t na = lo ? a : bx, nb = lo ? ax : b;
  a = na; b = nb;
#endif
}
static __device__ __forceinline__ float pswap_add(float x) {
  uint32_t a = __float_as_uint(x), b = a; pswap(a, b);
  return __uint_as_float(a) + __uint_as_float(b);
}
static __device__ __forceinline__ uint32_t cvtpk(float lo, float hi_) {
  uint32_t r;
  asm("v_cvt_pk_bf16_f32 %0, %1, %2" : "=v"(r) : "v"(lo), "v"(hi_));
  return r;
}
static __device__ __forceinline__ f32x16 mfma32(bf16x8 a, bf16x8 b, f32x16 c) {
  return __builtin_amdgcn_mfma_f32_32x32x16_bf16(a, b, c, 0, 0, 0);
}

// ---------------- convert f32 -> bf16 (pure streaming, 8 el/thread) ----------------
__global__ __launch_bounds__(256) void convert_kernel(
    const float* __restrict__ H, const float* __restrict__ wq,
    const float* __restrict__ wk, const float* __restrict__ wv,
    const float* __restrict__ wo,
    u16* __restrict__ Hb, u16* __restrict__ Wqkv, u16* __restrict__ Wob) {
  const size_t NHEL = (size_t)MM * DD;     // 6291456 (mult of 8)
  const size_t NW = (size_t)DD * DD;       // 589824  (mult of 8)
  size_t i = ((size_t)blockIdx.x * 256 + threadIdx.x) * 8;
  const float* src; u16* dst; size_t so, dofs;
  if (i < NHEL) { src = H; so = i; dst = Hb; dofs = i; }
  else if (i < NHEL + 3 * NW) {
    size_t j = i - NHEL; dst = Wqkv; dofs = j;
    if (j < NW) { src = wq; so = j; }
    else if (j < 2 * NW) { src = wk; so = j - NW; }
    else { src = wv; so = j - 2 * NW; }
  } else if (i < NHEL + 4 * NW) {
    size_t j = i - NHEL - 3 * NW; src = wo; so = j; dst = Wob; dofs = j;
  } else return;
  float4 v0 = *(const float4*)&src[so];
  float4 v1 = *(const float4*)&src[so + 4];
  union { u16 u[8]; uint4 v; } o;
  o.u[0] = f2b(v0.x); o.u[1] = f2b(v0.y); o.u[2] = f2b(v0.z); o.u[3] = f2b(v0.w);
  o.u[4] = f2b(v1.x); o.u[5] = f2b(v1.y); o.u[6] = f2b(v1.z); o.u[7] = f2b(v1.w);
  *(uint4*)&dst[dofs] = o.v;
}

// ---------------- GEMM (MODE 0): QKV proj, 128x128 tile, XCD-swizzled grid ----------------
__global__ __launch_bounds__(256) void gemm0_kernel(
    const u16* __restrict__ A, const u16* __restrict__ Bw,
    u16* __restrict__ Qp, u16* __restrict__ Kp, u16* __restrict__ Vt,
    const float* __restrict__ Pp, const float* __restrict__ Sp,
    const float* __restrict__ compat, const float* __restrict__ gamma) {
  __shared__ u16 SMEM[17408];                 // As(8192) + Bs(8192); Ct overlays (128*136)
  u16* As = SMEM;
  u16* Bs = SMEM + 8192;
  const int tid = threadIdx.x;
  const int lane = tid & 63, w = tid >> 6;
  const int wr = w >> 1, wc = w & 1;
  const int g = lane >> 4, r = lane & 15;
  const int lin = blockIdx.x;
  const int swz = (lin & 7) * 144 + (lin >> 3);
  const int m0 = (swz / 18) * 128, n0 = (swz % 18) * 128;

  f32x4 acc[4][4];
#pragma unroll
  for (int m = 0; m < 4; ++m)
#pragma unroll
    for (int n = 0; n < 4; ++n) acc[m][n] = (f32x4){0.f, 0.f, 0.f, 0.f};

  for (int ks = 0; ks < 12; ++ks) {
    const int k0 = ks * 64;
    __syncthreads();
#pragma unroll
    for (int ii = 0; ii < 4; ++ii) {
      int seg = (w * 4 + ii) * 64 + lane;
      int row = seg >> 3, cs = seg & 7;
      int csw = cs ^ (row & 7);
      // each gload16 covers 64 lanes x 16B = 1024B = 512 u16 -> dest stride *512
      gload16(&A[(size_t)(m0 + row) * DD + k0 + csw * 8], &As[(w * 4 + ii) * 512]);
      gload16(&Bw[(size_t)(n0 + row) * DD + k0 + csw * 8], &Bs[(w * 4 + ii) * 512]);
    }
    __syncthreads();
#pragma unroll
    for (int kk = 0; kk < 2; ++kk) {
      bf16x8 af[4], bfr[4];
#pragma unroll
      for (int m = 0; m < 4; ++m) {
        int row = wr * 64 + m * 16 + r;
        int ch = (kk * 4 + g) ^ (row & 7);
        af[m] = *(const bf16x8*)&As[row * 64 + ch * 8];
      }
#pragma unroll
      for (int n = 0; n < 4; ++n) {
        int row = wc * 64 + n * 16 + r;
        int ch = (kk * 4 + g) ^ (row & 7);
        bfr[n] = *(const bf16x8*)&Bs[row * 64 + ch * 8];
      }
#pragma unroll
      for (int m = 0; m < 4; ++m)
#pragma unroll
        for (int n = 0; n < 4; ++n)
          acc[m][n] = __builtin_amdgcn_mfma_f32_16x16x32_bf16(af[m], bfr[n], acc[m][n], 0, 0, 0);
    }
  }

  const int sel = n0 / DD;            // 0=Q 1=K 2=V  (tiles never straddle)
  const int e0b = n0 - sel * DD;      // head-block base, h0 = e0b>>6
  const int bb = m0 >> 11;            // batch
  const int tb = m0 & (TT - 1);       // token base (multiple of 128)
  __syncthreads();                    // all LDS reads of As/Bs done
#pragma unroll
  for (int m = 0; m < 4; ++m) {
#pragma unroll
    for (int n = 0; n < 4; ++n) {
#pragma unroll
      for (int reg = 0; reg < 4; ++reg) {
        float v = acc[m][n][reg];
        int t = wr * 64 + m * 16 + g * 4 + reg;   // local token 0..127
        int c = wc * 64 + n * 16 + r;             // local N col 0..127
        u16 bv = f2b(sel == 0 ? v * 0.18033688f : v);  // Q: *0.125*log2(e)
        if (sel < 2) SMEM[t * 136 + c] = bv;      // Ct[t][c]
        else         SMEM[c * 136 + t] = bv;      // Ct[dh][t] (transposed)
      }
    }
  }
  __syncthreads();
  if (sel < 2) {
    u16* base = (sel == 0) ? Qp : Kp;
    const int grp = tid >> 3, li = tid & 7;       // 32 groups x 8 lanes
#pragma unroll
    for (int it = 0; it < 8; ++it) {
      int chunk = it * 32 + grp;                  // 0..255
      int t = chunk & 127, hh = chunk >> 7;
      int h = (e0b >> 6) + hh;
      size_t row = ((size_t)(bb * NHEAD + h) * TT + tb + t) * DP;
      uint4 d = *(const uint4*)&SMEM[t * 136 + hh * 64 + li * 8];
      *(uint4*)&base[row + li * 8] = d;
    }
    // ---- bias dims 64..79: one (t,hh) chunk per thread, 32B each ----
    {
      const float L2E = 1.44269504f;
      int t = tid & 127, hh = tid >> 7;
      int h = (e0b >> 6) + hh;
      size_t ip = (size_t)bb * TT + tb + t;
      float p0 = Pp[ip * 2], p1 = Pp[ip * 2 + 1];
      union { u16 u[8]; uint4 v; } bias;
      union { u16 u[8]; uint4 v; } zz;
#pragma unroll
      for (int z = 0; z < 8; ++z) zz.u[z] = 0;
      if (sel == 0) {
        float c00 = compat[h * 4 + 0], c01 = compat[h * 4 + 1];
        float c10 = compat[h * 4 + 2], c11 = compat[h * 4 + 3];
        u16 q0 = f2b((p0 * c00 + p1 * c10) * L2E);
        u16 q1 = f2b((p0 * c01 + p1 * c11) * L2E);
        u16 gmb = f2b(gamma[0] * L2E);
        bias.u[0] = q0; bias.u[1] = q0; bias.u[2] = q1; bias.u[3] = q1;
        bias.u[4] = gmb; bias.u[5] = gmb; bias.u[6] = 0; bias.u[7] = 0;
      } else {
        float sv = Sp[ip];
        u16 p0h = f2b(p0); u16 p0l = f2b(p0 - b2f(p0h));
        u16 p1h = f2b(p1); u16 p1l = f2b(p1 - b2f(p1h));
        u16 svh = f2b(sv); u16 svl = f2b(sv - b2f(svh));
        bias.u[0] = p0h; bias.u[1] = p0l; bias.u[2] = p1h; bias.u[3] = p1l;
        bias.u[4] = svh; bias.u[5] = svl; bias.u[6] = 0; bias.u[7] = 0;
      }
      size_t row = ((size_t)(bb * NHEAD + h) * TT + tb + t) * DP;
      *(uint4*)&base[row + 64] = bias.v;
      *(uint4*)&base[row + 72] = zz.v;
    }
  } else {
    const int grp = tid >> 4, li = tid & 15;      // 16 groups x 16 lanes
#pragma unroll
    for (int it = 0; it < 8; ++it) {
      int c = it * 16 + grp;                      // 0..127
      int h = (e0b >> 6) + (c >> 6), dh = c & 63;
      size_t row = ((size_t)(bb * NHEAD + h)) * DH * TT + (size_t)dh * TT + tb;
      uint4 d = *(const uint4*)&SMEM[c * 136 + li * 8];
      *(uint4*)&Vt[row + li * 8] = d;
    }
  }
}

// ---------------- GEMM (MODE 1): out-proj, 64x128 tile, 768 blocks (3/CU) ----
__global__ __launch_bounds__(256) void gemm1_kernel(
    const u16* __restrict__ A, const u16* __restrict__ Bw,
    const float* __restrict__ bo, float* __restrict__ Out) {
  __shared__ u16 SMEM[12288];                 // As 64x64 (4096) + Bs 128x64 (8192)
  u16* As = SMEM;
  u16* Bs = SMEM + 4096;
  const int tid = threadIdx.x;
  const int lane = tid & 63, w = tid >> 6;
  const int wr = w & 1, wc = w >> 1;          // wave: 32(M) x 64(N)
  const int g = lane >> 4, r = lane & 15;
  const int m0 = blockIdx.x * 64, n0 = blockIdx.y * 128;

  f32x4 acc[2][4];
#pragma unroll
  for (int m = 0; m < 2; ++m)
#pragma unroll
    for (int n = 0; n < 4; ++n) acc[m][n] = (f32x4){0.f, 0.f, 0.f, 0.f};

  for (int ks = 0; ks < 12; ++ks) {
    const int k0 = ks * 64;
    __syncthreads();
#pragma unroll
    for (int i = 0; i < 6; ++i) {             // 24 chunks over 4 waves
      int idx = w + 4 * i;
      if (idx < 8) {                          // A chunks 0..7 (64 rows)
        int n = idx * 64 + lane;
        int row = n >> 3, cs = n & 7;
        int csw = cs ^ (row & 7);
        gload16(&A[(size_t)(m0 + row) * DD + k0 + csw * 8], &As[idx * 512]);
      } else {                                // B chunks 0..15 (128 rows)
        int j = idx - 8;
        int n = j * 64 + lane;
        int row = n >> 3, cs = n & 7;
        int csw = cs ^ (row & 7);
        gload16(&Bw[(size_t)(n0 + row) * DD + k0 + csw * 8], &Bs[j * 512]);
      }
    }
    __syncthreads();
#pragma unroll
    for (int kk = 0; kk < 2; ++kk) {
      bf16x8 af[2], bfr[4];
#pragma unroll
      for (int m = 0; m < 2; ++m) {
        int row = wr * 32 + m * 16 + r;
        int ch = (kk * 4 + g) ^ (row & 7);
        af[m] = *(const bf16x8*)&As[row * 64 + ch * 8];
      }
#pragma unroll
      for (int n = 0; n < 4; ++n) {
        int row = wc * 64 + n * 16 + r;
        int ch = (kk * 4 + g) ^ (row & 7);
        bfr[n] = *(const bf16x8*)&Bs[row * 64 + ch * 8];
      }
#pragma unroll
      for (int m = 0; m < 2; ++m)
#pragma unroll
        for (int n = 0; n < 4; ++n)
          acc[m][n] = __builtin_amdgcn_mfma_f32_16x16x32_bf16(af[m], bfr[n], acc[m][n], 0, 0, 0);
    }
  }

#pragma unroll
  for (int m = 0; m < 2; ++m) {
#pragma unroll
    for (int n = 0; n < 4; ++n) {
#pragma unroll
      for (int reg = 0; reg < 4; ++reg) {
        int gt = m0 + wr * 32 + m * 16 + g * 4 + reg;
        int e = n0 + wc * 64 + n * 16 + r;
        Out[(size_t)gt * DD + e] = acc[m][n][reg] + bo[e];
      }
    }
  }
}

// ---------------- attention: swapped QK^T, fixed-base softmax (m=0) ----------------
// R4-proven loop structure: 4 waves x 32 q, full 64-key tile per wave, single
// barrier per tile, K/V double-buffered via global_load_lds. l is accumulated
// on the VALU from the in-register f32 p values (R2-proven numerics): per-tile
// partial sum, ONE pswap_add cross-half combine at the end, and a 16-bpermute
// broadcast in the epilogue. This removes the 4 ones-MFMAs/tile (18% of the
// MFMA pipe) and frees 16 accumulator registers.
#define QB 128
__global__ __launch_bounds__(256, 3) void attn_kernel(
    const u16* __restrict__ Qp, const u16* __restrict__ Kp, const u16* __restrict__ Vtb,
    u16* __restrict__ Ctx) {
  __shared__ u16 Ks[2][64 * 88];   // 64 rows x 176B (160B data + 16B pad-dup)
  __shared__ u16 Vs[2][64 * 64];   // [dh][key], source pre-swizzled
  const int tid = threadIdx.x, lane = tid & 63, w = tid >> 6;
  const int hi = lane >> 5, ql = lane & 31;
  const int bid = blockIdx.x;
  const int bh = bid % 48, qb = bid / 48;   // bh-major: same bh -> same XCD
  const int b = bh / NHEAD, h = bh % NHEAD;

  const char* KgB = (const char*)(Kp + (size_t)bh * TT * DP);
  const char* VgB = (const char*)(Vtb + (size_t)bh * DH * TT);
  const u16* Qg = Qp + (size_t)bh * TT * DP;

  const int q = qb * QB + w * 32 + ql;
  bf16x8 Qf[5];
#pragma unroll
  for (int kbl = 0; kbl < 5; ++kbl)
    Qf[kbl] = *(const bf16x8*)&Qg[(size_t)q * DP + (2 * kbl + hi) * 8];

  auto kofs = [&](int i) {
    int n = i * 64 + lane;
    int rr = (n * 2979) >> 15;       // n/11 exact for n<768
    int c = n - 11 * rr; if (c > 9) c = 9;
    return rr * 160 + c * 16;
  };
  auto vofs = [&](int j) {
    int n = j * 64 + lane;
    int dh = n >> 3, cs = n & 7;
    return dh * 4096 + (cs ^ (dh & 7)) * 16;
  };
  const int koff0 = kofs(w), koff1 = kofs(w + 4), koff2 = (w < 3) ? kofs(w + 8) : 0;
  const int voff0 = vofs(w), voff1 = vofs(w + 4);

  auto STAGE = [&](int nb, int t0) {
    const char* ksrc = KgB + (size_t)t0 * 160;
    char* kd = (char*)&Ks[nb][0];
    gload16(ksrc + koff0, kd + w * 1024);
    gload16(ksrc + koff1, kd + (w + 4) * 1024);
    if (w < 3) gload16(ksrc + koff2, kd + (w + 8) * 1024);
    const char* vsrc = VgB + (size_t)t0 * 2;
    char* vd = (char*)&Vs[nb][0];
    gload16(vsrc + voff0, vd + w * 1024);
    gload16(vsrc + voff1, vd + (w + 4) * 1024);
  };

  f32x16 o0, o1;
#pragma unroll
  for (int z = 0; z < 16; ++z) { o0[z] = 0.f; o1[z] = 0.f; }
  float l_st = 0.f;                 // per-lane partial l for q = ql (own hi-parity keys)

  STAGE(0, 0);

  for (int kt = 0; kt < 32; ++kt) {
    __syncthreads();                       // drains vmcnt: current buffers valid
    if (kt + 1 < 32) STAGE((kt + 1) & 1, (kt + 1) * 64);
    const u16* Kb_ = &Ks[kt & 1][0];
    const u16* Vb_ = &Vs[kt & 1][0];

    // S^T = K' * Q'^T : rows=keys, cols=q (lane&31). Two 32-key blocks.
    f32x16 s0, s1;
#pragma unroll
    for (int z = 0; z < 16; ++z) { s0[z] = 0.f; s1[z] = 0.f; }
    __builtin_amdgcn_s_setprio(1);
#pragma unroll
    for (int kbl = 0; kbl < 5; ++kbl) {
      bf16x8 a0 = *(const bf16x8*)&Kb_[ql * 88 + hi * 8 + kbl * 16];
      s0 = mfma32(a0, Qf[kbl], s0);
    }
#pragma unroll
    for (int kbl = 0; kbl < 5; ++kbl) {
      bf16x8 a1 = *(const bf16x8*)&Kb_[(ql + 32) * 88 + hi * 8 + kbl * 16];
      s1 = mfma32(a1, Qf[kbl], s1);
    }
    __builtin_amdgcn_s_setprio(0);

    // P = exp2(S) directly (fixed base m=0); VALU l partial sum
    float p_[32];
#pragma unroll
    for (int z = 0; z < 16; ++z) p_[z] = EXP2(s0[z]);
#pragma unroll
    for (int z = 0; z < 16; ++z) p_[16 + z] = EXP2(s1[z]);
    float ts = 0.f;
#pragma unroll
    for (int z = 0; z < 32; ++z) ts += p_[z];
    l_st += ts;

    // build PA fragments in-register (cvt_pk + permlane32_swap); PV
    __builtin_amdgcn_s_setprio(1);
#pragma unroll
    for (int ks = 0; ks < 4; ++ks) {
      const int base = ks * 8;
      uint32_t wa = cvtpk(p_[base + 0], p_[base + 1]);
      uint32_t wb = cvtpk(p_[base + 4], p_[base + 5]);
      uint32_t wc = cvtpk(p_[base + 2], p_[base + 3]);
      uint32_t wd = cvtpk(p_[base + 6], p_[base + 7]);
      pswap(wa, wb);
      pswap(wc, wd);
      union { uint32_t u[4]; bf16x8 v; } pa;
      pa.u[0] = wa; pa.u[1] = wc; pa.u[2] = wb; pa.u[3] = wd;
#pragma unroll
      for (int nb = 0; nb < 2; ++nb) {
        int row = ql + 32 * nb;
        bf16x8 vf = *(const bf16x8*)&Vb_[row * 64 + (((2 * ks + hi) ^ (ql & 7)) * 8)];
        if (nb == 0) o0 = mfma32(pa.v, vf, o0);
        else         o1 = mfma32(pa.v, vf, o1);
      }
    }
    __builtin_amdgcn_s_setprio(0);
  }

  // epilogue: combine hi-halves of l once, broadcast 1/l from lane q2
  float lfull = pswap_add(l_st);            // lanes ql and ql+32 both hold l(q=ql)
  float invl = 1.0f / lfull;
#pragma unroll
  for (int z = 0; z < 16; ++z) {
    int q2 = (z & 3) + 8 * (z >> 2) + 4 * hi;
    float il = __uint_as_float(__builtin_amdgcn_ds_bpermute(q2 * 4, __float_as_uint(invl)));
    int qrow = qb * QB + w * 32 + q2;
    size_t rowb = ((size_t)b * TT + qrow) * DD + h * DH;
    Ctx[rowb + ql]      = f2b(o0[z] * il);
    Ctx[rowb + ql + 32] = f2b(o1[z] * il);
  }
}

extern "C" void kernel_launch(void* const* d_in, const int* in_sizes, int n_in,
                              void* d_out, int out_size, void* d_ws, size_t ws_size,
                              hipStream_t stream) {
  const float* H = (const float*)d_in[0];
  const float* p = (const float*)d_in[1];
  const float* s = (const float*)d_in[2];
  const float* wq = (const float*)d_in[3];
  const float* wk = (const float*)d_in[4];
  const float* wv = (const float*)d_in[5];
  const float* wo = (const float*)d_in[6];
  const float* bo = (const float*)d_in[7];
  const float* compat = (const float*)d_in[8];
  const float* gamma = (const float*)d_in[9];
  float* out = (float*)d_out;

  char* ws = (char*)d_ws;
  u16* Hb   = (u16*)(ws);               // 12,582,912 B (dead after gemm0 -> Ctx)
  u16* Wqkv = (u16*)(ws + 12582912);    //  3,538,944 B
  u16* Wob  = (u16*)(ws + 16121856);    //  1,179,648 B
  u16* Qpb  = (u16*)(ws + 17301504);    // 15,728,640 B  (B*H*T*80 bf16)
  u16* Kpb  = (u16*)(ws + 33030144);    // 15,728,640 B
  u16* Vtb  = (u16*)(ws + 48758784);    // 12,582,912 B  (written transposed by gemm0)
  u16* Ctx  = Hb;                       // alias: Hb dead after gemm0
  // total 61,341,696 B

  convert_kernel<<<4224, 256, 0, stream>>>(H, wq, wk, wv, wo, Hb, Wqkv, Wob);
  gemm0_kernel<<<1152, 256, 0, stream>>>(Hb, Wqkv, Qpb, Kpb, Vtb, p, s, compat, gamma);
  attn_kernel<<<768, 256, 0, stream>>>(Qpb, Kpb, Vtb, Ctx);
  gemm1_kernel<<<dim3(128, 6), 256, 0, stream>>>(Ctx, Wob, bo, out);
}